// Round 10
// baseline (206.737 us; speedup 1.0000x reference)
//
#include <hip/hip_runtime.h>
#include <hip/hip_bf16.h>

// ---------------------------------------------------------------------------
// MultiheadAttention: [T=2048, B=2, E=1024], H=16, D=64
// R10: split-KV attention (2 halves x 1024 keys) — doubles resident waves to
// 4/SIMD so dependency stalls cross-fill; halves merge via a small kernel
// (valid because the R7 no-max softmax is linear in partials). Attn core =
// R8 config (KVB=64, 32KB LDS dbuf, counted vmcnt, cross-tile PV defer).
// GEMMs as R8 (dbuf + counted vmcnt + setprio).
// ---------------------------------------------------------------------------

typedef __attribute__((ext_vector_type(8))) short short8;
typedef __attribute__((ext_vector_type(4))) float f32x4;
typedef __attribute__((ext_vector_type(16))) float f32x16;
typedef __attribute__((ext_vector_type(4))) unsigned u32x4;

#define T_DIM 2048
#define B_DIM 2
#define E_DIM 1024
#define H_DIM 16
#define D_DIM 64
#define M_ROWS (T_DIM * B_DIM)      // 4096
#define QKV_N (3 * E_DIM)           // 3072
#define HEAD_ELEMS (32 * 2048 * 64) // per q/k/v buffer elements (4,194,304)
#define LOG2E 1.44269504088896340736f

__device__ __forceinline__ unsigned short f2bf(float f) {
    unsigned u = __builtin_bit_cast(unsigned, f);
    unsigned r = (u + 0x7fffu + ((u >> 16) & 1u)) >> 16;
    return (unsigned short)r;
}

__device__ __forceinline__ float bf2f(unsigned short s) {
    unsigned u = ((unsigned)s) << 16;
    return __builtin_bit_cast(float, u);
}

__device__ __forceinline__ unsigned cvt_pk_bf16(float lo, float hi) {
    unsigned d;
    asm("v_cvt_pk_bf16_f32 %0, %1, %2" : "=v"(d) : "v"(lo), "v"(hi));
    return d;
}

__device__ __forceinline__ void gload_lds16(const void* g, void* l) {
    __builtin_amdgcn_global_load_lds(
        (const __attribute__((address_space(1))) void*)g,
        (__attribute__((address_space(3))) void*)l, 16, 0, 0);
}

__device__ __forceinline__ f32x16 mfma32(short8 a, short8 b, f32x16 c) {
    return __builtin_amdgcn_mfma_f32_32x32x16_bf16(a, b, c, 0, 0, 0);
}

// ---------------------------------------------------------------------------
// Cast / pack kernel. Wq gets 0.125 * log2(e) so softmax can use exp2.
// ---------------------------------------------------------------------------
__global__ __launch_bounds__(256) void cast_all(
    const float* __restrict__ X,
    const float* __restrict__ Wq, const float* __restrict__ Wk,
    const float* __restrict__ Wv, const float* __restrict__ Wo,
    unsigned short* __restrict__ Xbf,
    unsigned short* __restrict__ Wcat,
    unsigned short* __restrict__ Wobf)
{
    int idx = blockIdx.x * 256 + threadIdx.x;      // 0 .. 1M-1
    size_t base = (size_t)idx * 8;
    int row = (int)(base >> 10);
    int col = (int)(base & 1023);
    const float* src;
    unsigned short* dst;
    float scale = 1.0f;
    if (row < 4096) {
        src = X + base;
        dst = Xbf + base;
    } else if (row < 7168) {
        int wrow = row - 4096;                      // 0..3071
        if (wrow < 1024)      { src = Wq + ((size_t)wrow << 10) + col; scale = 0.125f * LOG2E; }
        else if (wrow < 2048) { src = Wk + ((size_t)(wrow - 1024) << 10) + col; }
        else                  { src = Wv + ((size_t)(wrow - 2048) << 10) + col; }
        dst = Wcat + ((size_t)wrow << 10) + col;
    } else {
        int wrow = row - 7168;                      // 0..1023
        src = Wo + ((size_t)wrow << 10) + col;
        dst = Wobf + ((size_t)wrow << 10) + col;
    }
    float4 f0 = *(const float4*)src;
    float4 f1 = *(const float4*)(src + 4);
    short8 r;
    r[0] = (short)f2bf(f0.x * scale);
    r[1] = (short)f2bf(f0.y * scale);
    r[2] = (short)f2bf(f0.z * scale);
    r[3] = (short)f2bf(f0.w * scale);
    r[4] = (short)f2bf(f1.x * scale);
    r[5] = (short)f2bf(f1.y * scale);
    r[6] = (short)f2bf(f1.z * scale);
    r[7] = (short)f2bf(f1.w * scale);
    *(short8*)dst = r;
}

__global__ __launch_bounds__(256) void bias_fuse(
    const float* __restrict__ bq, const float* __restrict__ bk,
    const float* __restrict__ bv, float* __restrict__ biasq)
{
    int i = blockIdx.x * 256 + threadIdx.x;
    if (i < 1024)       biasq[i] = 0.125f * LOG2E * bq[i];
    else if (i < 2048)  biasq[i] = bk[i - 1024];
    else if (i < 3072)  biasq[i] = bv[i - 2048];
}

// ---------------------------------------------------------------------------
// GEMM: C[M,N] = A[M,K] @ B[N,K]^T + bias[N]
//   MODE 0: q,k -> [BH][T][D] bf16 ; v -> transposed+key-permuted vTp[BH][D][T]
//   MODE 1: out = fp32 row-major [M][N]
// 128x128 tile, BK=32, dbuf LDS, counted vmcnt, raw barriers, setprio.
// ---------------------------------------------------------------------------
template <int MODE>
__global__ __launch_bounds__(256) void gemm_bt(
    const unsigned short* __restrict__ A,
    const unsigned short* __restrict__ B,
    const float* __restrict__ bias,
    void* __restrict__ outp,
    int M, int N, int K)
{
    __shared__ alignas(16) unsigned short As[2][128 * 32];
    __shared__ alignas(16) unsigned short Bs[2][128 * 32];
    const int tid = threadIdx.x;
    const int wave = tid >> 6, lane = tid & 63;
    const int lr = lane & 15, lg = lane >> 4;
    const int nbx = N >> 7;
    const int bx = blockIdx.x % nbx, by = blockIdx.x / nbx;
    const int wr = wave >> 1, wc = wave & 1;

    f32x4 acc[4][4] = {};

    auto stage = [&](int buf, int kt) {
#pragma unroll
        for (int pass = 0; pass < 2; ++pass) {
            int c = pass * 256 + wave * 64 + lane;       // 16B chunk id 0..511
            int row = c >> 2, kc = c & 3;
            gload_lds16(A + (size_t)(by * 128 + row) * K + kt + kc * 8,
                        (char*)&As[buf][0] + c * 16);
            gload_lds16(B + (size_t)(bx * 128 + row) * K + kt + kc * 8,
                        (char*)&Bs[buf][0] + c * 16);
        }
    };

    const int NK = K >> 5;
    stage(0, 0);
    for (int ki = 0; ki < NK; ++ki) {
        const int buf = ki & 1;
        if (ki < NK - 1) {
            stage(buf ^ 1, (ki + 1) * 32);
            asm volatile("s_waitcnt vmcnt(4)" ::: "memory");
        } else {
            asm volatile("s_waitcnt vmcnt(0)" ::: "memory");
        }
        __builtin_amdgcn_s_barrier();
        __builtin_amdgcn_sched_barrier(0);

        short8 af[4], bf[4];
#pragma unroll
        for (int m = 0; m < 4; ++m)
            af[m] = *(const short8*)&As[buf][(wr * 64 + m * 16 + lr) * 32 + lg * 8];
#pragma unroll
        for (int n = 0; n < 4; ++n)
            bf[n] = *(const short8*)&Bs[buf][(wc * 64 + n * 16 + lr) * 32 + lg * 8];
        __builtin_amdgcn_s_setprio(1);
#pragma unroll
        for (int m = 0; m < 4; ++m)
#pragma unroll
            for (int n = 0; n < 4; ++n)
                acc[m][n] = __builtin_amdgcn_mfma_f32_16x16x32_bf16(af[m], bf[n], acc[m][n], 0, 0, 0);
        __builtin_amdgcn_s_setprio(0);

        asm volatile("s_waitcnt lgkmcnt(0)" ::: "memory");
        __builtin_amdgcn_sched_barrier(0);
        __builtin_amdgcn_s_barrier();
    }

    const int gcol0 = bx * 128 + wc * 64;
    const int grow0 = by * 128 + wr * 64;
    if (MODE == 0) {
        unsigned short* qb = (unsigned short*)outp;
#pragma unroll
        for (int m = 0; m < 4; ++m) {
#pragma unroll
            for (int n = 0; n < 4; ++n) {
                int col = gcol0 + n * 16 + lr;           // 0..3071
                float bsv = bias[col];
                int which = col >> 10;
                int e = col & 1023;
                int h = e >> 6, d = e & 63;
                if (which < 2) {
                    unsigned short* bufb = qb + (size_t)which * HEAD_ELEMS;
#pragma unroll
                    for (int j = 0; j < 4; ++j) {
                        int r = grow0 + m * 16 + lg * 4 + j; // 0..4095 = t*2+b
                        int t = r >> 1, b = r & 1;
                        int bh = b * 16 + h;
                        bufb[((size_t)bh * 2048 + t) * 64 + d] = f2bf(acc[m][n][j] + bsv);
                    }
                } else {
                    // v: write transposed vTp[bh][d][t] with key bits2,3 swapped;
                    // pack (t0, t0+1) per dword -> swap dword-index bits 1,2.
                    unsigned* vT32 = (unsigned*)(qb + (size_t)2 * HEAD_ELEMS);
                    int t0 = (grow0 + m * 16 + lg * 4) >> 1;    // even
                    int dwidx = t0 >> 1;
                    int dwp = (dwidx & ~6) | ((dwidx & 2) << 1) | ((dwidx & 4) >> 1);
                    unsigned w0 = (unsigned)f2bf(acc[m][n][0] + bsv) |
                                  ((unsigned)f2bf(acc[m][n][2] + bsv) << 16);  // b=0
                    unsigned w1 = (unsigned)f2bf(acc[m][n][1] + bsv) |
                                  ((unsigned)f2bf(acc[m][n][3] + bsv) << 16);  // b=1
                    vT32[(size_t)(h * 64 + d) * 1024 + dwp] = w0;
                    vT32[(size_t)((16 + h) * 64 + d) * 1024 + dwp] = w1;
                }
            }
        }
    } else {
        float* O = (float*)outp;
#pragma unroll
        for (int m = 0; m < 4; ++m) {
#pragma unroll
            for (int n = 0; n < 4; ++n) {
                int col = gcol0 + n * 16 + lr;
                float bsv = bias[col];
#pragma unroll
                for (int j = 0; j < 4; ++j) {
                    int r = grow0 + m * 16 + lg * 4 + j;
                    O[(size_t)r * N + col] = acc[m][n][j] + bsv;
                }
            }
        }
    }
}

// ---------------------------------------------------------------------------
// Flash attention, split-KV: grid = 32 bh x 16 q-tiles x 2 KV-halves.
// Block 256 = 4 waves x 32 q-rows; each block does 16 chunks of 64 keys in
// [half*1024, half*1024+1024). Writes UNNORMALIZED O (bf16) + row sums l
// (fp32); a merge kernel combines halves (valid: no-max softmax is linear).
// ---------------------------------------------------------------------------
struct AttnCtx {
    const unsigned short* kh;
    const unsigned short* vh;
    int tid, ql, hi;
};

template<bool DO_PV>
__device__ __forceinline__ void attn_step(
    const AttnCtx& cx, int t, int kv0,
    unsigned short (*Ks)[64 * 64], unsigned short (*Vs)[64 * 64],
    const short8 (&qv)[4],
    const short8 (&vfP)[8], const short8 (&paP)[4],
    short8 (&vfC)[8], short8 (&paC)[4],
    f32x16 (&accO)[2], float& lrun)
{
    const int buf = t & 1;
    const int tid = cx.tid, ql = cx.ql, hi = cx.hi;
    if (t < 15) {
        const int kt = kv0 + (t + 1) * 64;
#pragma unroll
        for (int p = 0; p < 2; ++p) {          // K tile [64 k][64 d]
            int c = p * 256 + tid;
            int row = c >> 3;
            int sxb = ((c & 7) * 16) ^ ((row & 7) << 4);
            gload_lds16(cx.kh + (size_t)(kt + row) * 64 + (sxb >> 1),
                        (char*)&Ks[buf ^ 1][0] + c * 16);
        }
#pragma unroll
        for (int p = 0; p < 2; ++p) {          // V^T tile [64 d][64 k]
            int c = p * 256 + tid;
            int d = c >> 3;
            int sxb = ((c & 7) * 16) ^ ((d & 7) << 4);
            gload_lds16(cx.vh + (size_t)d * 2048 + kt + (sxb >> 1),
                        (char*)&Vs[buf ^ 1][0] + c * 16);
        }
        asm volatile("s_waitcnt vmcnt(4)" ::: "memory");
    } else {
        asm volatile("s_waitcnt vmcnt(0)" ::: "memory");
    }
    __builtin_amdgcn_s_barrier();
    __builtin_amdgcn_sched_barrier(0);

    const char* Kb = (const char*)&Ks[buf][0];
    const char* Vb = (const char*)&Vs[buf][0];

    // ---- S^T = K Q^T (matrix pipe) ----
    f32x16 st[2] = {};
    __builtin_amdgcn_s_setprio(1);
#pragma unroll
    for (int m = 0; m < 2; ++m) {
        int krow = m * 32 + ql;
#pragma unroll
        for (int c = 0; c < 4; ++c) {
            int bo = (krow * 128 + c * 32 + hi * 16) ^ ((krow & 7) << 4);
            short8 ka = *(const short8*)(Kb + bo);
            st[m] = mfma32(ka, qv[c], st[m]);
        }
    }
    // ---- V fragments of THIS tile -> registers (consumed next step) ----
#pragma unroll
    for (int n = 0; n < 2; ++n) {
        int d = n * 32 + ql;
#pragma unroll
        for (int kc = 0; kc < 4; ++kc) {
            int bo = (d * 128 + kc * 32 + hi * 16) ^ ((d & 7) << 4);
            vfC[n * 4 + kc] = *(const short8*)(Vb + bo);
        }
    }
    // ---- deferred PV of PREVIOUS tile (register-only, overlaps softmax) ----
    if constexpr (DO_PV) {
#pragma unroll
        for (int n = 0; n < 2; ++n)
#pragma unroll
            for (int kc = 0; kc < 4; ++kc)
                accO[n] = mfma32(vfP[n * 4 + kc], paP[kc], accO[n]);
    }
    __builtin_amdgcn_s_setprio(0);
    __builtin_amdgcn_sched_barrier(0);

    // ---- softmax numerator: P = exp2(S), 4-way partial sums (no max) ----
    float rs0 = 0.f, rs1 = 0.f, rs2 = 0.f, rs3 = 0.f;
#pragma unroll
    for (int m = 0; m < 2; ++m) {
#pragma unroll
        for (int r = 0; r < 16; r += 4) {
            float e0 = __builtin_amdgcn_exp2f(st[m][r + 0]);
            float e1 = __builtin_amdgcn_exp2f(st[m][r + 1]);
            float e2 = __builtin_amdgcn_exp2f(st[m][r + 2]);
            float e3 = __builtin_amdgcn_exp2f(st[m][r + 3]);
            st[m][r + 0] = e0; st[m][r + 1] = e1;
            st[m][r + 2] = e2; st[m][r + 3] = e3;
            rs0 += e0; rs1 += e1; rs2 += e2; rs3 += e3;
        }
    }
    lrun += (rs0 + rs1) + (rs2 + rs3);

    // ---- pack P (lane-local thanks to key permutation) ----
#pragma unroll
    for (int kc = 0; kc < 4; ++kc) {
        int m = kc >> 1, b8 = (kc & 1) * 8;
        u32x4 u;
        u[0] = cvt_pk_bf16(st[m][b8 + 0], st[m][b8 + 1]);
        u[1] = cvt_pk_bf16(st[m][b8 + 2], st[m][b8 + 3]);
        u[2] = cvt_pk_bf16(st[m][b8 + 4], st[m][b8 + 5]);
        u[3] = cvt_pk_bf16(st[m][b8 + 6], st[m][b8 + 7]);
        paC[kc] = __builtin_bit_cast(short8, u);
    }

    // drain this tile's LDS reads before other waves' next stage overwrites
    asm volatile("s_waitcnt lgkmcnt(0)" ::: "memory");
    __builtin_amdgcn_sched_barrier(0);
    __builtin_amdgcn_s_barrier();
}

__global__ __launch_bounds__(256, 4) void attn_fwd(
    const unsigned short* __restrict__ q,
    const unsigned short* __restrict__ k,
    const unsigned short* __restrict__ vT,
    unsigned short* __restrict__ o0,   // half-0 unnorm O, [4096][1024] bf16
    unsigned short* __restrict__ o1,   // half-1 unnorm O
    float* __restrict__ lsum)          // [2][32][2048] fp32
{
    __shared__ alignas(16) unsigned short Ks[2][64 * 64];   // 8 KB each
    __shared__ alignas(16) unsigned short Vs[2][64 * 64];   // 8 KB each
    const int tid = threadIdx.x, wv = tid >> 6, l = tid & 63;
    const int ql = l & 31, hi = l >> 5;
    // XCD-aware remap: 4 heads per XCD; 32 slots/head = 16 q-tiles x 2 halves.
    const int lid = blockIdx.x;
    const int xcd = lid & 7, slot = lid >> 3;        // slot 0..127
    const int bh = xcd * 4 + (slot >> 5);            // 0..31 (= b*16+h)
    const int sub = slot & 31;
    const int q0 = (sub >> 1) * 128;
    const int half = sub & 1;
    const int kv0 = half * 1024;
    const unsigned short* qh = q + (size_t)bh * (2048 * 64);
    AttnCtx cx;
    cx.kh = k + (size_t)bh * (2048 * 64);
    cx.vh = vT + (size_t)bh * (64 * 2048);
    cx.tid = tid; cx.ql = ql; cx.hi = hi;

    // Q fragments: B-frag col = q (lane&31), k-elem = c*16 + hi*8 + e
    const int qrow = q0 + wv * 32 + ql;
    short8 qv[4];
#pragma unroll
    for (int c = 0; c < 4; ++c)
        qv[c] = *(const short8*)&qh[(size_t)qrow * 64 + c * 16 + hi * 8];

    f32x16 accO[2] = {};
    float lrun = 0.0f;
    short8 vfA[8], vfB[8], paA[4], paB[4];

    // ---- prologue: stage chunk 0 of this half ----
    {
#pragma unroll
        for (int p = 0; p < 2; ++p) {
            int c = p * 256 + tid;
            int row = c >> 3;
            int sxb = ((c & 7) * 16) ^ ((row & 7) << 4);
            gload_lds16(cx.kh + (size_t)(kv0 + row) * 64 + (sxb >> 1),
                        (char*)&Ks[0][0] + c * 16);
        }
#pragma unroll
        for (int p = 0; p < 2; ++p) {
            int c = p * 256 + tid;
            int d = c >> 3;
            int sxb = ((c & 7) * 16) ^ ((d & 7) << 4);
            gload_lds16(cx.vh + (size_t)d * 2048 + kv0 + (sxb >> 1),
                        (char*)&Vs[0][0] + c * 16);
        }
    }

    attn_step<false>(cx, 0, kv0, Ks, Vs, qv, vfB, paB, vfA, paA, accO, lrun);
    for (int t = 1; t < 15; t += 2) {
        attn_step<true>(cx, t,     kv0, Ks, Vs, qv, vfA, paA, vfB, paB, accO, lrun);
        attn_step<true>(cx, t + 1, kv0, Ks, Vs, qv, vfB, paB, vfA, paA, accO, lrun);
    }
    attn_step<true>(cx, 15, kv0, Ks, Vs, qv, vfA, paA, vfB, paB, accO, lrun);
    // final PV (last tile's fragments live in vfB/paB)
#pragma unroll
    for (int n = 0; n < 2; ++n)
#pragma unroll
        for (int kc = 0; kc < 4; ++kc)
            accO[n] = mfma32(vfB[n * 4 + kc], paB[kc], accO[n]);

    // ---- epilogue: write UNNORMALIZED O (bf16) + half row-sum (fp32) ----
    const float lh = lrun + __shfl_xor(lrun, 32);
    if (hi == 0)
        lsum[half * 65536 + bh * 2048 + qrow] = lh;
    unsigned short* outb = half ? o1 : o0;
    const int b = bh >> 4, h = bh & 15;
    const int orow = qrow * 2 + b;
#pragma unroll
    for (int n = 0; n < 2; ++n)
#pragma unroll
        for (int rq = 0; rq < 4; ++rq) {
            uint2 u;
            u.x = cvt_pk_bf16(accO[n][rq * 4 + 0], accO[n][rq * 4 + 1]);
            u.y = cvt_pk_bf16(accO[n][rq * 4 + 2], accO[n][rq * 4 + 3]);
            *(uint2*)&outb[(size_t)orow * 1024 + h * 64 + n * 32 + rq * 8 + hi * 4] = u;
        }
}

// ---------------------------------------------------------------------------
// Merge: ab = (O0 + O1) / (l0 + l1), bf16 out (in-place over o0 region).
// ---------------------------------------------------------------------------
__global__ __launch_bounds__(256) void merge_attn(
    const unsigned short* __restrict__ o1,
    const float* __restrict__ lsum,
    unsigned short* __restrict__ o0)   // read + write (elementwise)
{
    int idx = blockIdx.x * 256 + threadIdx.x;   // 0..524287
    size_t base = (size_t)idx * 8;
    int r = (int)(base >> 10), cb = (int)(base & 1023);
    int t = r >> 1, b = r & 1, h = cb >> 6;
    int bh = b * 16 + h;
    float l0 = lsum[bh * 2048 + t];
    float l1 = lsum[65536 + bh * 2048 + t];
    float inv = 1.0f / (l0 + l1);
    short8 x = *(const short8*)(o0 + base);
    short8 y = *(const short8*)(o1 + base);
    u32x4 u;
#pragma unroll
    for (int j = 0; j < 4; ++j) {
        float f0 = (bf2f((unsigned short)x[2*j])   + bf2f((unsigned short)y[2*j]))   * inv;
        float f1 = (bf2f((unsigned short)x[2*j+1]) + bf2f((unsigned short)y[2*j+1])) * inv;
        u[j] = cvt_pk_bf16(f0, f1);
    }
    *(short8*)(o0 + base) = __builtin_bit_cast(short8, u);
}

// ---------------------------------------------------------------------------
extern "C" void kernel_launch(void* const* d_in, const int* in_sizes, int n_in,
                              void* d_out, int out_size, void* d_ws, size_t ws_size,
                              hipStream_t stream) {
    const float* X  = (const float*)d_in[0];
    const float* Wq = (const float*)d_in[1];
    const float* bq = (const float*)d_in[2];
    const float* Wk = (const float*)d_in[3];
    const float* bk = (const float*)d_in[4];
    const float* Wv = (const float*)d_in[5];
    const float* bv = (const float*)d_in[6];
    const float* Wo = (const float*)d_in[7];
    const float* bo = (const float*)d_in[8];
    float* out = (float*)d_out;

    char* ws = (char*)d_ws;
    if (ws_size < ((size_t)49 << 20)) return;   // need ~48.1 MB scratch
    unsigned short* Xbf   = (unsigned short*)(ws);                       // 8 MB (reused: o1)
    unsigned short* Wcat  = (unsigned short*)(ws + ((size_t)8  << 20));  // 6 MB (reused: lsum)
    unsigned short* Wobf  = (unsigned short*)(ws + ((size_t)14 << 20));  // 2 MB
    unsigned short* qb    = (unsigned short*)(ws + ((size_t)16 << 20));  // q, k, vTp (8 MB each)
    unsigned short* ab    = (unsigned short*)(ws + ((size_t)40 << 20));  // 8 MB (o0 / merged)
    float*          biasq = (float*)(ws + ((size_t)48 << 20));           // 12 KB
    unsigned short* kb  = qb + (size_t)HEAD_ELEMS;
    unsigned short* vTb = qb + (size_t)2 * HEAD_ELEMS;
    unsigned short* o1   = Xbf;                   // dead after QKV GEMM
    float*          lsum = (float*)Wcat;          // dead after QKV GEMM (512 KB)

    cast_all<<<4096, 256, 0, stream>>>(X, Wq, Wk, Wv, Wo, Xbf, Wcat, Wobf);
    bias_fuse<<<12, 256, 0, stream>>>(bq, bk, bv, biasq);
    gemm_bt<0><<<dim3((M_ROWS / 128) * (QKV_N / 128)), 256, 0, stream>>>(
        Xbf, Wcat, biasq, (void*)qb, M_ROWS, QKV_N, E_DIM);
    attn_fwd<<<dim3(32 * 16 * 2), 256, 0, stream>>>(qb, kb, vTb, ab, o1, lsum);
    merge_attn<<<2048, 256, 0, stream>>>(o1, lsum, ab);
    gemm_bt<1><<<dim3((M_ROWS / 128) * (E_DIM / 128)), 256, 0, stream>>>(
        ab, Wobf, bo, (void*)out, M_ROWS, E_DIM, E_DIM);
}

// Round 11
// 127.633 us; speedup vs baseline: 1.6198x; 1.6198x over previous
//
#include <hip/hip_runtime.h>
#include <hip/hip_bf16.h>

// ---------------------------------------------------------------------------
// MultiheadAttention: [T=2048, B=2, E=1024], H=16, D=64
// R11: split-KV attention (2 halves) with V in a TRIPLE-buffered LDS ring so
// the deferred PV reads V(t-1) from LDS — no 64-VGPR register V state, fits
// the 128-VGPR cap of __launch_bounds__(256,4); grid 1024 = exactly 4
// blocks/CU (16 waves/CU). R10's spill disaster fixed. Merge kernel combines
// halves (no-max softmax is linear in partials). GEMMs as R8.
// ---------------------------------------------------------------------------

typedef __attribute__((ext_vector_type(8))) short short8;
typedef __attribute__((ext_vector_type(4))) float f32x4;
typedef __attribute__((ext_vector_type(16))) float f32x16;
typedef __attribute__((ext_vector_type(4))) unsigned u32x4;

#define T_DIM 2048
#define B_DIM 2
#define E_DIM 1024
#define H_DIM 16
#define D_DIM 64
#define M_ROWS (T_DIM * B_DIM)      // 4096
#define QKV_N (3 * E_DIM)           // 3072
#define HEAD_ELEMS (32 * 2048 * 64) // per q/k/v buffer elements (4,194,304)
#define LOG2E 1.44269504088896340736f

__device__ __forceinline__ unsigned short f2bf(float f) {
    unsigned u = __builtin_bit_cast(unsigned, f);
    unsigned r = (u + 0x7fffu + ((u >> 16) & 1u)) >> 16;
    return (unsigned short)r;
}

__device__ __forceinline__ float bf2f(unsigned short s) {
    unsigned u = ((unsigned)s) << 16;
    return __builtin_bit_cast(float, u);
}

__device__ __forceinline__ unsigned cvt_pk_bf16(float lo, float hi) {
    unsigned d;
    asm("v_cvt_pk_bf16_f32 %0, %1, %2" : "=v"(d) : "v"(lo), "v"(hi));
    return d;
}

__device__ __forceinline__ void gload_lds16(const void* g, void* l) {
    __builtin_amdgcn_global_load_lds(
        (const __attribute__((address_space(1))) void*)g,
        (__attribute__((address_space(3))) void*)l, 16, 0, 0);
}

__device__ __forceinline__ f32x16 mfma32(short8 a, short8 b, f32x16 c) {
    return __builtin_amdgcn_mfma_f32_32x32x16_bf16(a, b, c, 0, 0, 0);
}

// ---------------------------------------------------------------------------
// Cast / pack kernel. Wq gets 0.125 * log2(e) so softmax can use exp2.
// ---------------------------------------------------------------------------
__global__ __launch_bounds__(256) void cast_all(
    const float* __restrict__ X,
    const float* __restrict__ Wq, const float* __restrict__ Wk,
    const float* __restrict__ Wv, const float* __restrict__ Wo,
    unsigned short* __restrict__ Xbf,
    unsigned short* __restrict__ Wcat,
    unsigned short* __restrict__ Wobf)
{
    int idx = blockIdx.x * 256 + threadIdx.x;      // 0 .. 1M-1
    size_t base = (size_t)idx * 8;
    int row = (int)(base >> 10);
    int col = (int)(base & 1023);
    const float* src;
    unsigned short* dst;
    float scale = 1.0f;
    if (row < 4096) {
        src = X + base;
        dst = Xbf + base;
    } else if (row < 7168) {
        int wrow = row - 4096;                      // 0..3071
        if (wrow < 1024)      { src = Wq + ((size_t)wrow << 10) + col; scale = 0.125f * LOG2E; }
        else if (wrow < 2048) { src = Wk + ((size_t)(wrow - 1024) << 10) + col; }
        else                  { src = Wv + ((size_t)(wrow - 2048) << 10) + col; }
        dst = Wcat + ((size_t)wrow << 10) + col;
    } else {
        int wrow = row - 7168;                      // 0..1023
        src = Wo + ((size_t)wrow << 10) + col;
        dst = Wobf + ((size_t)wrow << 10) + col;
    }
    float4 f0 = *(const float4*)src;
    float4 f1 = *(const float4*)(src + 4);
    short8 r;
    r[0] = (short)f2bf(f0.x * scale);
    r[1] = (short)f2bf(f0.y * scale);
    r[2] = (short)f2bf(f0.z * scale);
    r[3] = (short)f2bf(f0.w * scale);
    r[4] = (short)f2bf(f1.x * scale);
    r[5] = (short)f2bf(f1.y * scale);
    r[6] = (short)f2bf(f1.z * scale);
    r[7] = (short)f2bf(f1.w * scale);
    *(short8*)dst = r;
}

__global__ __launch_bounds__(256) void bias_fuse(
    const float* __restrict__ bq, const float* __restrict__ bk,
    const float* __restrict__ bv, float* __restrict__ biasq)
{
    int i = blockIdx.x * 256 + threadIdx.x;
    if (i < 1024)       biasq[i] = 0.125f * LOG2E * bq[i];
    else if (i < 2048)  biasq[i] = bk[i - 1024];
    else if (i < 3072)  biasq[i] = bv[i - 2048];
}

// ---------------------------------------------------------------------------
// GEMM: C[M,N] = A[M,K] @ B[N,K]^T + bias[N]
//   MODE 0: q,k -> [BH][T][D] bf16 ; v -> transposed+key-permuted vTp[BH][D][T]
//   MODE 1: out = fp32 row-major [M][N]
// 128x128 tile, BK=32, dbuf LDS, counted vmcnt, raw barriers, setprio.
// ---------------------------------------------------------------------------
template <int MODE>
__global__ __launch_bounds__(256) void gemm_bt(
    const unsigned short* __restrict__ A,
    const unsigned short* __restrict__ B,
    const float* __restrict__ bias,
    void* __restrict__ outp,
    int M, int N, int K)
{
    __shared__ alignas(16) unsigned short As[2][128 * 32];
    __shared__ alignas(16) unsigned short Bs[2][128 * 32];
    const int tid = threadIdx.x;
    const int wave = tid >> 6, lane = tid & 63;
    const int lr = lane & 15, lg = lane >> 4;
    const int nbx = N >> 7;
    const int bx = blockIdx.x % nbx, by = blockIdx.x / nbx;
    const int wr = wave >> 1, wc = wave & 1;

    f32x4 acc[4][4] = {};

    auto stage = [&](int buf, int kt) {
#pragma unroll
        for (int pass = 0; pass < 2; ++pass) {
            int c = pass * 256 + wave * 64 + lane;       // 16B chunk id 0..511
            int row = c >> 2, kc = c & 3;
            gload_lds16(A + (size_t)(by * 128 + row) * K + kt + kc * 8,
                        (char*)&As[buf][0] + c * 16);
            gload_lds16(B + (size_t)(bx * 128 + row) * K + kt + kc * 8,
                        (char*)&Bs[buf][0] + c * 16);
        }
    };

    const int NK = K >> 5;
    stage(0, 0);
    for (int ki = 0; ki < NK; ++ki) {
        const int buf = ki & 1;
        if (ki < NK - 1) {
            stage(buf ^ 1, (ki + 1) * 32);
            asm volatile("s_waitcnt vmcnt(4)" ::: "memory");
        } else {
            asm volatile("s_waitcnt vmcnt(0)" ::: "memory");
        }
        __builtin_amdgcn_s_barrier();
        __builtin_amdgcn_sched_barrier(0);

        short8 af[4], bf[4];
#pragma unroll
        for (int m = 0; m < 4; ++m)
            af[m] = *(const short8*)&As[buf][(wr * 64 + m * 16 + lr) * 32 + lg * 8];
#pragma unroll
        for (int n = 0; n < 4; ++n)
            bf[n] = *(const short8*)&Bs[buf][(wc * 64 + n * 16 + lr) * 32 + lg * 8];
        __builtin_amdgcn_s_setprio(1);
#pragma unroll
        for (int m = 0; m < 4; ++m)
#pragma unroll
            for (int n = 0; n < 4; ++n)
                acc[m][n] = __builtin_amdgcn_mfma_f32_16x16x32_bf16(af[m], bf[n], acc[m][n], 0, 0, 0);
        __builtin_amdgcn_s_setprio(0);

        asm volatile("s_waitcnt lgkmcnt(0)" ::: "memory");
        __builtin_amdgcn_sched_barrier(0);
        __builtin_amdgcn_s_barrier();
    }

    const int gcol0 = bx * 128 + wc * 64;
    const int grow0 = by * 128 + wr * 64;
    if (MODE == 0) {
        unsigned short* qb = (unsigned short*)outp;
#pragma unroll
        for (int m = 0; m < 4; ++m) {
#pragma unroll
            for (int n = 0; n < 4; ++n) {
                int col = gcol0 + n * 16 + lr;           // 0..3071
                float bsv = bias[col];
                int which = col >> 10;
                int e = col & 1023;
                int h = e >> 6, d = e & 63;
                if (which < 2) {
                    unsigned short* bufb = qb + (size_t)which * HEAD_ELEMS;
#pragma unroll
                    for (int j = 0; j < 4; ++j) {
                        int r = grow0 + m * 16 + lg * 4 + j; // 0..4095 = t*2+b
                        int t = r >> 1, b = r & 1;
                        int bh = b * 16 + h;
                        bufb[((size_t)bh * 2048 + t) * 64 + d] = f2bf(acc[m][n][j] + bsv);
                    }
                } else {
                    // v: write transposed vTp[bh][d][t] with key bits2,3 swapped;
                    // pack (t0, t0+1) per dword -> swap dword-index bits 1,2.
                    unsigned* vT32 = (unsigned*)(qb + (size_t)2 * HEAD_ELEMS);
                    int t0 = (grow0 + m * 16 + lg * 4) >> 1;    // even
                    int dwidx = t0 >> 1;
                    int dwp = (dwidx & ~6) | ((dwidx & 2) << 1) | ((dwidx & 4) >> 1);
                    unsigned w0 = (unsigned)f2bf(acc[m][n][0] + bsv) |
                                  ((unsigned)f2bf(acc[m][n][2] + bsv) << 16);  // b=0
                    unsigned w1 = (unsigned)f2bf(acc[m][n][1] + bsv) |
                                  ((unsigned)f2bf(acc[m][n][3] + bsv) << 16);  // b=1
                    vT32[(size_t)(h * 64 + d) * 1024 + dwp] = w0;
                    vT32[(size_t)((16 + h) * 64 + d) * 1024 + dwp] = w1;
                }
            }
        }
    } else {
        float* O = (float*)outp;
#pragma unroll
        for (int m = 0; m < 4; ++m) {
#pragma unroll
            for (int n = 0; n < 4; ++n) {
                int col = gcol0 + n * 16 + lr;
                float bsv = bias[col];
#pragma unroll
                for (int j = 0; j < 4; ++j) {
                    int r = grow0 + m * 16 + lg * 4 + j;
                    O[(size_t)r * N + col] = acc[m][n][j] + bsv;
                }
            }
        }
    }
}

// ---------------------------------------------------------------------------
// Flash attention, split-KV: grid = 32 bh x 16 q-tiles x 2 KV-halves.
// K double-buffered (2x8KB), V TRIPLE-buffered (3x8KB) in LDS = 40KB/block ->
// 4 blocks/CU. PV of tile t-1 reads V(t-1) straight from the LDS ring
// (valid: overwritten only at step t+1), so no V register state.
// ---------------------------------------------------------------------------
struct AttnCtx {
    const unsigned short* kh;
    const unsigned short* vh;
    int tid, ql, hi;
};

template<bool DO_PV, bool DO_STAGE>
__device__ __forceinline__ void attn_step(
    const AttnCtx& cx, int kt_next,
    const char* Kb, const char* Vprv,
    char* Kst, char* Vst,
    const short8 (&qv)[4],
    const short8 (&paP)[4], short8 (&paC)[4],
    f32x16 (&accO)[2], float& lrun)
{
    const int tid = cx.tid, ql = cx.ql, hi = cx.hi;
    if constexpr (DO_STAGE) {
#pragma unroll
        for (int p = 0; p < 2; ++p) {          // K tile [64 k][64 d]
            int c = p * 256 + tid;
            int row = c >> 3;
            int sxb = ((c & 7) * 16) ^ ((row & 7) << 4);
            gload_lds16(cx.kh + (size_t)(kt_next + row) * 64 + (sxb >> 1), Kst + c * 16);
        }
#pragma unroll
        for (int p = 0; p < 2; ++p) {          // V^T tile [64 d][64 k]
            int c = p * 256 + tid;
            int d = c >> 3;
            int sxb = ((c & 7) * 16) ^ ((d & 7) << 4);
            gload_lds16(cx.vh + (size_t)d * 2048 + kt_next + (sxb >> 1), Vst + c * 16);
        }
        asm volatile("s_waitcnt vmcnt(4)" ::: "memory");
    } else {
        asm volatile("s_waitcnt vmcnt(0)" ::: "memory");
    }
    __builtin_amdgcn_s_barrier();
    __builtin_amdgcn_sched_barrier(0);

    // ---- S^T = K Q^T (matrix pipe) ----
    f32x16 st[2] = {};
    __builtin_amdgcn_s_setprio(1);
#pragma unroll
    for (int m = 0; m < 2; ++m) {
        int krow = m * 32 + ql;
#pragma unroll
        for (int c = 0; c < 4; ++c) {
            int bo = (krow * 128 + c * 32 + hi * 16) ^ ((krow & 7) << 4);
            short8 ka = *(const short8*)(Kb + bo);
            st[m] = mfma32(ka, qv[c], st[m]);
        }
    }
    // ---- deferred PV of PREVIOUS tile, V read from LDS ring ----
    if constexpr (DO_PV) {
#pragma unroll
        for (int n = 0; n < 2; ++n) {
            int d = n * 32 + ql;
#pragma unroll
            for (int kc = 0; kc < 4; ++kc) {
                int bo = (d * 128 + kc * 32 + hi * 16) ^ ((d & 7) << 4);
                short8 va = *(const short8*)(Vprv + bo);
                accO[n] = mfma32(va, paP[kc], accO[n]);
            }
        }
    }
    __builtin_amdgcn_s_setprio(0);
    __builtin_amdgcn_sched_barrier(0);

    // ---- softmax numerator: P = exp2(S), 4-way partial sums (no max) ----
    float rs0 = 0.f, rs1 = 0.f, rs2 = 0.f, rs3 = 0.f;
#pragma unroll
    for (int m = 0; m < 2; ++m) {
#pragma unroll
        for (int r = 0; r < 16; r += 4) {
            float e0 = __builtin_amdgcn_exp2f(st[m][r + 0]);
            float e1 = __builtin_amdgcn_exp2f(st[m][r + 1]);
            float e2 = __builtin_amdgcn_exp2f(st[m][r + 2]);
            float e3 = __builtin_amdgcn_exp2f(st[m][r + 3]);
            st[m][r + 0] = e0; st[m][r + 1] = e1;
            st[m][r + 2] = e2; st[m][r + 3] = e3;
            rs0 += e0; rs1 += e1; rs2 += e2; rs3 += e3;
        }
    }
    lrun += (rs0 + rs1) + (rs2 + rs3);

    // ---- pack P (lane-local thanks to key permutation) ----
#pragma unroll
    for (int kc = 0; kc < 4; ++kc) {
        int m = kc >> 1, b8 = (kc & 1) * 8;
        u32x4 u;
        u[0] = cvt_pk_bf16(st[m][b8 + 0], st[m][b8 + 1]);
        u[1] = cvt_pk_bf16(st[m][b8 + 2], st[m][b8 + 3]);
        u[2] = cvt_pk_bf16(st[m][b8 + 4], st[m][b8 + 5]);
        u[3] = cvt_pk_bf16(st[m][b8 + 6], st[m][b8 + 7]);
        paC[kc] = __builtin_bit_cast(short8, u);
    }

    // drain this step's LDS reads before other waves' next stage overwrites
    asm volatile("s_waitcnt lgkmcnt(0)" ::: "memory");
    __builtin_amdgcn_sched_barrier(0);
    __builtin_amdgcn_s_barrier();
}

__global__ __launch_bounds__(256, 4) void attn_fwd(
    const unsigned short* __restrict__ q,
    const unsigned short* __restrict__ k,
    const unsigned short* __restrict__ vT,
    unsigned short* __restrict__ o0,   // half-0 unnorm O, [4096][1024] bf16
    unsigned short* __restrict__ o1,   // half-1 unnorm O
    float* __restrict__ lsum)          // [2][32][2048] fp32
{
    __shared__ alignas(16) unsigned short Ks[2][64 * 64];   // 8 KB each
    __shared__ alignas(16) unsigned short Vs[3][64 * 64];   // 8 KB each
    const int tid = threadIdx.x, wv = tid >> 6, l = tid & 63;
    const int ql = l & 31, hi = l >> 5;
    // XCD-aware remap: 4 heads per XCD; 32 slots/head = 16 q-tiles x 2 halves.
    const int lid = blockIdx.x;
    const int xcd = lid & 7, slot = lid >> 3;        // slot 0..127
    const int bh = xcd * 4 + (slot >> 5);            // 0..31 (= b*16+h)
    const int sub = slot & 31;
    const int q0 = (sub >> 1) * 128;
    const int half = sub & 1;
    const int kv0 = half * 1024;
    const unsigned short* qh = q + (size_t)bh * (2048 * 64);
    AttnCtx cx;
    cx.kh = k + (size_t)bh * (2048 * 64);
    cx.vh = vT + (size_t)bh * (64 * 2048);
    cx.tid = tid; cx.ql = ql; cx.hi = hi;

    char* K0 = (char*)&Ks[0][0];
    char* K1 = (char*)&Ks[1][0];
    char* V0 = (char*)&Vs[0][0];
    char* V1 = (char*)&Vs[1][0];
    char* V2 = (char*)&Vs[2][0];
    auto VB = [&](int i) -> char* { return i == 0 ? V0 : (i == 1 ? V1 : V2); };

    // Q fragments: B-frag col = q (lane&31), k-elem = c*16 + hi*8 + e
    const int qrow = q0 + wv * 32 + ql;
    short8 qv[4];
#pragma unroll
    for (int c = 0; c < 4; ++c)
        qv[c] = *(const short8*)&qh[(size_t)qrow * 64 + c * 16 + hi * 8];

    f32x16 accO[2] = {};
    float lrun = 0.0f;
    short8 paA[4], paB[4];

    // ---- prologue: stage tile 0 -> K0, V0 ----
    {
#pragma unroll
        for (int p = 0; p < 2; ++p) {
            int c = p * 256 + tid;
            int row = c >> 3;
            int sxb = ((c & 7) * 16) ^ ((row & 7) << 4);
            gload_lds16(cx.kh + (size_t)(kv0 + row) * 64 + (sxb >> 1), K0 + c * 16);
        }
#pragma unroll
        for (int p = 0; p < 2; ++p) {
            int c = p * 256 + tid;
            int d = c >> 3;
            int sxb = ((c & 7) * 16) ^ ((d & 7) << 4);
            gload_lds16(cx.vh + (size_t)d * 2048 + kv0 + (sxb >> 1), V0 + c * 16);
        }
    }

    // V ring indices: at entry to step t, vp=(t-1)%3, vn=(t+1)%3.
    int vp = 2, vn = 1;
    int vc = 0;
    auto rot = [&]() { vp = vc; vc = vn; vn = (vn == 2) ? 0 : vn + 1; };

    // step 0: stage tile 1 -> K1, VB(1); QK(0); no PV; pack -> paA
    attn_step<false, true>(cx, kv0 + 64, K0, nullptr, K1, VB(vn), qv, paB, paA, accO, lrun);
    rot();
    for (int t = 1; t < 15; t += 2) {
        // odd step t: Kb=K1, Vprv=V(t-1); stage tile t+1 -> K0, VB(vn); pack -> paB
        attn_step<true, true>(cx, kv0 + (t + 1) * 64, K1, VB(vp), K0, VB(vn),
                              qv, paA, paB, accO, lrun);
        rot();
        // even step t+1: Kb=K0; stage tile t+2 -> K1, VB(vn); pack -> paA
        attn_step<true, true>(cx, kv0 + (t + 2) * 64, K0, VB(vp), K1, VB(vn),
                              qv, paB, paA, accO, lrun);
        rot();
    }
    // step 15: Kb=K1, Vprv=V(14); no staging; pack -> paB
    attn_step<true, false>(cx, 0, K1, VB(vp), nullptr, nullptr, qv, paA, paB, accO, lrun);
    // final PV(15): V(15) lives in Vs[15%3] = V0
#pragma unroll
    for (int n = 0; n < 2; ++n) {
        int d = n * 32 + ql;
#pragma unroll
        for (int kc = 0; kc < 4; ++kc) {
            int bo = (d * 128 + kc * 32 + hi * 16) ^ ((d & 7) << 4);
            short8 va = *(const short8*)(V0 + bo);
            accO[n] = mfma32(va, paB[kc], accO[n]);
        }
    }

    // ---- epilogue: write UNNORMALIZED O (bf16) + half row-sum (fp32) ----
    const float lh = lrun + __shfl_xor(lrun, 32);
    if (hi == 0)
        lsum[half * 65536 + bh * 2048 + qrow] = lh;
    unsigned short* outb = half ? o1 : o0;
    const int b = bh >> 4, h = bh & 15;
    const int orow = qrow * 2 + b;
#pragma unroll
    for (int n = 0; n < 2; ++n)
#pragma unroll
        for (int rq = 0; rq < 4; ++rq) {
            uint2 u;
            u.x = cvt_pk_bf16(accO[n][rq * 4 + 0], accO[n][rq * 4 + 1]);
            u.y = cvt_pk_bf16(accO[n][rq * 4 + 2], accO[n][rq * 4 + 3]);
            *(uint2*)&outb[(size_t)orow * 1024 + h * 64 + n * 32 + rq * 8 + hi * 4] = u;
        }
}

// ---------------------------------------------------------------------------
// Merge: ab = (O0 + O1) / (l0 + l1), bf16 out (in-place over o0 region).
// ---------------------------------------------------------------------------
__global__ __launch_bounds__(256) void merge_attn(
    const unsigned short* __restrict__ o1,
    const float* __restrict__ lsum,
    unsigned short* __restrict__ o0)   // read + write (elementwise)
{
    int idx = blockIdx.x * 256 + threadIdx.x;   // 0..524287
    size_t base = (size_t)idx * 8;
    int r = (int)(base >> 10), cb = (int)(base & 1023);
    int t = r >> 1, b = r & 1, h = cb >> 6;
    int bh = b * 16 + h;
    float l0 = lsum[bh * 2048 + t];
    float l1 = lsum[65536 + bh * 2048 + t];
    float inv = 1.0f / (l0 + l1);
    short8 x = *(const short8*)(o0 + base);
    short8 y = *(const short8*)(o1 + base);
    u32x4 u;
#pragma unroll
    for (int j = 0; j < 4; ++j) {
        float f0 = (bf2f((unsigned short)x[2*j])   + bf2f((unsigned short)y[2*j]))   * inv;
        float f1 = (bf2f((unsigned short)x[2*j+1]) + bf2f((unsigned short)y[2*j+1])) * inv;
        u[j] = cvt_pk_bf16(f0, f1);
    }
    *(short8*)(o0 + base) = __builtin_bit_cast(short8, u);
}

// ---------------------------------------------------------------------------
extern "C" void kernel_launch(void* const* d_in, const int* in_sizes, int n_in,
                              void* d_out, int out_size, void* d_ws, size_t ws_size,
                              hipStream_t stream) {
    const float* X  = (const float*)d_in[0];
    const float* Wq = (const float*)d_in[1];
    const float* bq = (const float*)d_in[2];
    const float* Wk = (const float*)d_in[3];
    const float* bk = (const float*)d_in[4];
    const float* Wv = (const float*)d_in[5];
    const float* bv = (const float*)d_in[6];
    const float* Wo = (const float*)d_in[7];
    const float* bo = (const float*)d_in[8];
    float* out = (float*)d_out;

    char* ws = (char*)d_ws;
    if (ws_size < ((size_t)49 << 20)) return;   // need ~48.1 MB scratch
    unsigned short* Xbf   = (unsigned short*)(ws);                       // 8 MB (reused: o1)
    unsigned short* Wcat  = (unsigned short*)(ws + ((size_t)8  << 20));  // 6 MB (reused: lsum)
    unsigned short* Wobf  = (unsigned short*)(ws + ((size_t)14 << 20));  // 2 MB
    unsigned short* qb    = (unsigned short*)(ws + ((size_t)16 << 20));  // q, k, vTp (8 MB each)
    unsigned short* ab    = (unsigned short*)(ws + ((size_t)40 << 20));  // 8 MB (o0 / merged)
    float*          biasq = (float*)(ws + ((size_t)48 << 20));           // 12 KB
    unsigned short* kb  = qb + (size_t)HEAD_ELEMS;
    unsigned short* vTb = qb + (size_t)2 * HEAD_ELEMS;
    unsigned short* o1   = Xbf;                   // dead after QKV GEMM
    float*          lsum = (float*)Wcat;          // dead after QKV GEMM (512 KB)

    cast_all<<<4096, 256, 0, stream>>>(X, Wq, Wk, Wv, Wo, Xbf, Wcat, Wobf);
    bias_fuse<<<12, 256, 0, stream>>>(bq, bk, bv, biasq);
    gemm_bt<0><<<dim3((M_ROWS / 128) * (QKV_N / 128)), 256, 0, stream>>>(
        Xbf, Wcat, biasq, (void*)qb, M_ROWS, QKV_N, E_DIM);
    attn_fwd<<<dim3(32 * 16 * 2), 256, 0, stream>>>(qb, kb, vTb, ab, o1, lsum);
    merge_attn<<<2048, 256, 0, stream>>>(o1, lsum, ab);
    gemm_bt<1><<<dim3((M_ROWS / 128) * (E_DIM / 128)), 256, 0, stream>>>(
        ab, Wobf, bo, (void*)out, M_ROWS, E_DIM, E_DIM);
}

// Round 12
// 126.838 us; speedup vs baseline: 1.6299x; 1.0063x over previous
//
#include <hip/hip_runtime.h>
#include <hip/hip_bf16.h>

// ---------------------------------------------------------------------------
// MultiheadAttention: [T=2048, B=2, E=1024], H=16, D=64
// R12: single-pass attn (split-KV reverted) with DOUBLE-Q waves: each wave
// owns 64 q-rows; K fragments are read once into registers and reused for 2
// QK MFMAs, V fragments read once (LDS 3-slot ring) and reused for 2 PV
// MFMAs — halves LDS-pipe traffic per FLOP (the R11-diagnosed bottleneck).
// Grid 256 = 1 block/CU. Rest: swapped-QK^T 32x32x16, sigma-permuted V,
// no-max exp2 softmax, cross-tile PV defer, XCD remap; GEMMs as R8.
// ---------------------------------------------------------------------------

typedef __attribute__((ext_vector_type(8))) short short8;
typedef __attribute__((ext_vector_type(4))) float f32x4;
typedef __attribute__((ext_vector_type(16))) float f32x16;
typedef __attribute__((ext_vector_type(4))) unsigned u32x4;

#define T_DIM 2048
#define B_DIM 2
#define E_DIM 1024
#define H_DIM 16
#define D_DIM 64
#define M_ROWS (T_DIM * B_DIM)      // 4096
#define QKV_N (3 * E_DIM)           // 3072
#define HEAD_ELEMS (32 * 2048 * 64) // per q/k/v buffer elements (4,194,304)
#define LOG2E 1.44269504088896340736f

__device__ __forceinline__ unsigned short f2bf(float f) {
    unsigned u = __builtin_bit_cast(unsigned, f);
    unsigned r = (u + 0x7fffu + ((u >> 16) & 1u)) >> 16;
    return (unsigned short)r;
}

__device__ __forceinline__ unsigned cvt_pk_bf16(float lo, float hi) {
    unsigned d;
    asm("v_cvt_pk_bf16_f32 %0, %1, %2" : "=v"(d) : "v"(lo), "v"(hi));
    return d;
}

__device__ __forceinline__ void gload_lds16(const void* g, void* l) {
    __builtin_amdgcn_global_load_lds(
        (const __attribute__((address_space(1))) void*)g,
        (__attribute__((address_space(3))) void*)l, 16, 0, 0);
}

__device__ __forceinline__ f32x16 mfma32(short8 a, short8 b, f32x16 c) {
    return __builtin_amdgcn_mfma_f32_32x32x16_bf16(a, b, c, 0, 0, 0);
}

// ---------------------------------------------------------------------------
// Cast / pack kernel. Wq gets 0.125 * log2(e) so softmax can use exp2.
// ---------------------------------------------------------------------------
__global__ __launch_bounds__(256) void cast_all(
    const float* __restrict__ X,
    const float* __restrict__ Wq, const float* __restrict__ Wk,
    const float* __restrict__ Wv, const float* __restrict__ Wo,
    unsigned short* __restrict__ Xbf,
    unsigned short* __restrict__ Wcat,
    unsigned short* __restrict__ Wobf)
{
    int idx = blockIdx.x * 256 + threadIdx.x;      // 0 .. 1M-1
    size_t base = (size_t)idx * 8;
    int row = (int)(base >> 10);
    int col = (int)(base & 1023);
    const float* src;
    unsigned short* dst;
    float scale = 1.0f;
    if (row < 4096) {
        src = X + base;
        dst = Xbf + base;
    } else if (row < 7168) {
        int wrow = row - 4096;                      // 0..3071
        if (wrow < 1024)      { src = Wq + ((size_t)wrow << 10) + col; scale = 0.125f * LOG2E; }
        else if (wrow < 2048) { src = Wk + ((size_t)(wrow - 1024) << 10) + col; }
        else                  { src = Wv + ((size_t)(wrow - 2048) << 10) + col; }
        dst = Wcat + ((size_t)wrow << 10) + col;
    } else {
        int wrow = row - 7168;                      // 0..1023
        src = Wo + ((size_t)wrow << 10) + col;
        dst = Wobf + ((size_t)wrow << 10) + col;
    }
    float4 f0 = *(const float4*)src;
    float4 f1 = *(const float4*)(src + 4);
    short8 r;
    r[0] = (short)f2bf(f0.x * scale);
    r[1] = (short)f2bf(f0.y * scale);
    r[2] = (short)f2bf(f0.z * scale);
    r[3] = (short)f2bf(f0.w * scale);
    r[4] = (short)f2bf(f1.x * scale);
    r[5] = (short)f2bf(f1.y * scale);
    r[6] = (short)f2bf(f1.z * scale);
    r[7] = (short)f2bf(f1.w * scale);
    *(short8*)dst = r;
}

__global__ __launch_bounds__(256) void bias_fuse(
    const float* __restrict__ bq, const float* __restrict__ bk,
    const float* __restrict__ bv, float* __restrict__ biasq)
{
    int i = blockIdx.x * 256 + threadIdx.x;
    if (i < 1024)       biasq[i] = 0.125f * LOG2E * bq[i];
    else if (i < 2048)  biasq[i] = bk[i - 1024];
    else if (i < 3072)  biasq[i] = bv[i - 2048];
}

// ---------------------------------------------------------------------------
// GEMM: C[M,N] = A[M,K] @ B[N,K]^T + bias[N]
//   MODE 0: q,k -> [BH][T][D] bf16 ; v -> transposed+key-permuted vTp[BH][D][T]
//   MODE 1: out = fp32 row-major [M][N]
// 128x128 tile, BK=32, dbuf LDS, counted vmcnt, raw barriers, setprio.
// ---------------------------------------------------------------------------
template <int MODE>
__global__ __launch_bounds__(256) void gemm_bt(
    const unsigned short* __restrict__ A,
    const unsigned short* __restrict__ B,
    const float* __restrict__ bias,
    void* __restrict__ outp,
    int M, int N, int K)
{
    __shared__ alignas(16) unsigned short As[2][128 * 32];
    __shared__ alignas(16) unsigned short Bs[2][128 * 32];
    const int tid = threadIdx.x;
    const int wave = tid >> 6, lane = tid & 63;
    const int lr = lane & 15, lg = lane >> 4;
    const int nbx = N >> 7;
    const int bx = blockIdx.x % nbx, by = blockIdx.x / nbx;
    const int wr = wave >> 1, wc = wave & 1;

    f32x4 acc[4][4] = {};

    auto stage = [&](int buf, int kt) {
#pragma unroll
        for (int pass = 0; pass < 2; ++pass) {
            int c = pass * 256 + wave * 64 + lane;       // 16B chunk id 0..511
            int row = c >> 2, kc = c & 3;
            gload_lds16(A + (size_t)(by * 128 + row) * K + kt + kc * 8,
                        (char*)&As[buf][0] + c * 16);
            gload_lds16(B + (size_t)(bx * 128 + row) * K + kt + kc * 8,
                        (char*)&Bs[buf][0] + c * 16);
        }
    };

    const int NK = K >> 5;
    stage(0, 0);
    for (int ki = 0; ki < NK; ++ki) {
        const int buf = ki & 1;
        if (ki < NK - 1) {
            stage(buf ^ 1, (ki + 1) * 32);
            asm volatile("s_waitcnt vmcnt(4)" ::: "memory");
        } else {
            asm volatile("s_waitcnt vmcnt(0)" ::: "memory");
        }
        __builtin_amdgcn_s_barrier();
        __builtin_amdgcn_sched_barrier(0);

        short8 af[4], bf[4];
#pragma unroll
        for (int m = 0; m < 4; ++m)
            af[m] = *(const short8*)&As[buf][(wr * 64 + m * 16 + lr) * 32 + lg * 8];
#pragma unroll
        for (int n = 0; n < 4; ++n)
            bf[n] = *(const short8*)&Bs[buf][(wc * 64 + n * 16 + lr) * 32 + lg * 8];
        __builtin_amdgcn_s_setprio(1);
#pragma unroll
        for (int m = 0; m < 4; ++m)
#pragma unroll
            for (int n = 0; n < 4; ++n)
                acc[m][n] = __builtin_amdgcn_mfma_f32_16x16x32_bf16(af[m], bf[n], acc[m][n], 0, 0, 0);
        __builtin_amdgcn_s_setprio(0);

        asm volatile("s_waitcnt lgkmcnt(0)" ::: "memory");
        __builtin_amdgcn_sched_barrier(0);
        __builtin_amdgcn_s_barrier();
    }

    const int gcol0 = bx * 128 + wc * 64;
    const int grow0 = by * 128 + wr * 64;
    if (MODE == 0) {
        unsigned short* qb = (unsigned short*)outp;
#pragma unroll
        for (int m = 0; m < 4; ++m) {
#pragma unroll
            for (int n = 0; n < 4; ++n) {
                int col = gcol0 + n * 16 + lr;           // 0..3071
                float bsv = bias[col];
                int which = col >> 10;
                int e = col & 1023;
                int h = e >> 6, d = e & 63;
                if (which < 2) {
                    unsigned short* bufb = qb + (size_t)which * HEAD_ELEMS;
#pragma unroll
                    for (int j = 0; j < 4; ++j) {
                        int r = grow0 + m * 16 + lg * 4 + j; // 0..4095 = t*2+b
                        int t = r >> 1, b = r & 1;
                        int bh = b * 16 + h;
                        bufb[((size_t)bh * 2048 + t) * 64 + d] = f2bf(acc[m][n][j] + bsv);
                    }
                } else {
                    // v: write transposed vTp[bh][d][t] with key bits2,3 swapped;
                    // pack (t0, t0+1) per dword -> swap dword-index bits 1,2.
                    unsigned* vT32 = (unsigned*)(qb + (size_t)2 * HEAD_ELEMS);
                    int t0 = (grow0 + m * 16 + lg * 4) >> 1;    // even
                    int dwidx = t0 >> 1;
                    int dwp = (dwidx & ~6) | ((dwidx & 2) << 1) | ((dwidx & 4) >> 1);
                    unsigned w0 = (unsigned)f2bf(acc[m][n][0] + bsv) |
                                  ((unsigned)f2bf(acc[m][n][2] + bsv) << 16);  // b=0
                    unsigned w1 = (unsigned)f2bf(acc[m][n][1] + bsv) |
                                  ((unsigned)f2bf(acc[m][n][3] + bsv) << 16);  // b=1
                    vT32[(size_t)(h * 64 + d) * 1024 + dwp] = w0;
                    vT32[(size_t)((16 + h) * 64 + d) * 1024 + dwp] = w1;
                }
            }
        }
    } else {
        float* O = (float*)outp;
#pragma unroll
        for (int m = 0; m < 4; ++m) {
#pragma unroll
            for (int n = 0; n < 4; ++n) {
                int col = gcol0 + n * 16 + lr;
                float bsv = bias[col];
#pragma unroll
                for (int j = 0; j < 4; ++j) {
                    int r = grow0 + m * 16 + lg * 4 + j;
                    O[(size_t)r * N + col] = acc[m][n][j] + bsv;
                }
            }
        }
    }
}

// ---------------------------------------------------------------------------
// Flash attention, double-Q: grid = 32 bh x 8 q-tiles(256 rows), 1 block/CU.
// Block 256 = 4 waves x 64 q-rows (2 Q-blocks per wave). K fragments read
// once into registers, reused for both Q-blocks; V from a 3-slot LDS ring,
// each fragment reused for both PV MFMAs. K double-buffered LDS. 40 KB LDS.
// ---------------------------------------------------------------------------
struct AttnCtx {
    const unsigned short* kh;
    const unsigned short* vh;
    int tid, ql, hi;
};

template<bool DO_PV, bool DO_STAGE>
__device__ __forceinline__ void attn_step(
    const AttnCtx& cx, int kt_next,
    const char* Kb, const char* Vprv,
    char* Kst, char* Vst,
    const short8 (&qv0)[4], const short8 (&qv1)[4],
    const short8 (&paP0)[4], const short8 (&paP1)[4],
    short8 (&paC0)[4], short8 (&paC1)[4],
    f32x16 (&accO0)[2], f32x16 (&accO1)[2],
    float& lrun0, float& lrun1)
{
    const int tid = cx.tid, ql = cx.ql, hi = cx.hi;
    if constexpr (DO_STAGE) {
#pragma unroll
        for (int p = 0; p < 2; ++p) {          // K tile [64 k][64 d]
            int c = p * 256 + tid;
            int row = c >> 3;
            int sxb = ((c & 7) * 16) ^ ((row & 7) << 4);
            gload_lds16(cx.kh + (size_t)(kt_next + row) * 64 + (sxb >> 1), Kst + c * 16);
        }
#pragma unroll
        for (int p = 0; p < 2; ++p) {          // V^T tile [64 d][64 k]
            int c = p * 256 + tid;
            int d = c >> 3;
            int sxb = ((c & 7) * 16) ^ ((d & 7) << 4);
            gload_lds16(cx.vh + (size_t)d * 2048 + kt_next + (sxb >> 1), Vst + c * 16);
        }
        asm volatile("s_waitcnt vmcnt(4)" ::: "memory");
    } else {
        asm volatile("s_waitcnt vmcnt(0)" ::: "memory");
    }
    __builtin_amdgcn_s_barrier();
    __builtin_amdgcn_sched_barrier(0);

    // ---- K fragments once into registers (shared by both Q-blocks) ----
    short8 ka[8];
#pragma unroll
    for (int m = 0; m < 2; ++m) {
        int krow = m * 32 + ql;
#pragma unroll
        for (int c = 0; c < 4; ++c) {
            int bo = (krow * 128 + c * 32 + hi * 16) ^ ((krow & 7) << 4);
            ka[m * 4 + c] = *(const short8*)(Kb + bo);
        }
    }

    // ---- QK for both Q-blocks + deferred PV(prev), V frag read once ----
    f32x16 st0[2] = {}, st1[2] = {};
    __builtin_amdgcn_s_setprio(1);
#pragma unroll
    for (int m = 0; m < 2; ++m)
#pragma unroll
        for (int c = 0; c < 4; ++c)
            st0[m] = mfma32(ka[m * 4 + c], qv0[c], st0[m]);
    if constexpr (DO_PV) {
#pragma unroll
        for (int n = 0; n < 2; ++n) {
            int d = n * 32 + ql;
#pragma unroll
            for (int kc = 0; kc < 4; ++kc) {
                int bo = (d * 128 + kc * 32 + hi * 16) ^ ((d & 7) << 4);
                short8 va = *(const short8*)(Vprv + bo);
                accO0[n] = mfma32(va, paP0[kc], accO0[n]);
                accO1[n] = mfma32(va, paP1[kc], accO1[n]);
            }
        }
    }
#pragma unroll
    for (int m = 0; m < 2; ++m)
#pragma unroll
        for (int c = 0; c < 4; ++c)
            st1[m] = mfma32(ka[m * 4 + c], qv1[c], st1[m]);
    __builtin_amdgcn_s_setprio(0);

    // ---- softmax (no max, exp2 domain) + lane-local pack, per Q-block ----
    {
        float rs0 = 0.f, rs1 = 0.f, rs2 = 0.f, rs3 = 0.f;
#pragma unroll
        for (int m = 0; m < 2; ++m)
#pragma unroll
            for (int r = 0; r < 16; r += 4) {
                float e0 = __builtin_amdgcn_exp2f(st0[m][r + 0]);
                float e1 = __builtin_amdgcn_exp2f(st0[m][r + 1]);
                float e2 = __builtin_amdgcn_exp2f(st0[m][r + 2]);
                float e3 = __builtin_amdgcn_exp2f(st0[m][r + 3]);
                st0[m][r + 0] = e0; st0[m][r + 1] = e1;
                st0[m][r + 2] = e2; st0[m][r + 3] = e3;
                rs0 += e0; rs1 += e1; rs2 += e2; rs3 += e3;
            }
        lrun0 += (rs0 + rs1) + (rs2 + rs3);
#pragma unroll
        for (int kc = 0; kc < 4; ++kc) {
            int m = kc >> 1, b8 = (kc & 1) * 8;
            u32x4 u;
            u[0] = cvt_pk_bf16(st0[m][b8 + 0], st0[m][b8 + 1]);
            u[1] = cvt_pk_bf16(st0[m][b8 + 2], st0[m][b8 + 3]);
            u[2] = cvt_pk_bf16(st0[m][b8 + 4], st0[m][b8 + 5]);
            u[3] = cvt_pk_bf16(st0[m][b8 + 6], st0[m][b8 + 7]);
            paC0[kc] = __builtin_bit_cast(short8, u);
        }
    }
    {
        float rs0 = 0.f, rs1 = 0.f, rs2 = 0.f, rs3 = 0.f;
#pragma unroll
        for (int m = 0; m < 2; ++m)
#pragma unroll
            for (int r = 0; r < 16; r += 4) {
                float e0 = __builtin_amdgcn_exp2f(st1[m][r + 0]);
                float e1 = __builtin_amdgcn_exp2f(st1[m][r + 1]);
                float e2 = __builtin_amdgcn_exp2f(st1[m][r + 2]);
                float e3 = __builtin_amdgcn_exp2f(st1[m][r + 3]);
                st1[m][r + 0] = e0; st1[m][r + 1] = e1;
                st1[m][r + 2] = e2; st1[m][r + 3] = e3;
                rs0 += e0; rs1 += e1; rs2 += e2; rs3 += e3;
            }
        lrun1 += (rs0 + rs1) + (rs2 + rs3);
#pragma unroll
        for (int kc = 0; kc < 4; ++kc) {
            int m = kc >> 1, b8 = (kc & 1) * 8;
            u32x4 u;
            u[0] = cvt_pk_bf16(st1[m][b8 + 0], st1[m][b8 + 1]);
            u[1] = cvt_pk_bf16(st1[m][b8 + 2], st1[m][b8 + 3]);
            u[2] = cvt_pk_bf16(st1[m][b8 + 4], st1[m][b8 + 5]);
            u[3] = cvt_pk_bf16(st1[m][b8 + 6], st1[m][b8 + 7]);
            paC1[kc] = __builtin_bit_cast(short8, u);
        }
    }

    // drain this step's LDS reads before other waves' next stage overwrites
    asm volatile("s_waitcnt lgkmcnt(0)" ::: "memory");
    __builtin_amdgcn_sched_barrier(0);
    __builtin_amdgcn_s_barrier();
}

__global__ __launch_bounds__(256, 2) void attn_fwd(
    const unsigned short* __restrict__ q,
    const unsigned short* __restrict__ k,
    const unsigned short* __restrict__ vT,
    unsigned short* __restrict__ outb)   // [4096][1024] bf16, row=t*2+b, col=h*64+d
{
    __shared__ alignas(16) unsigned short Ks[2][64 * 64];   // 8 KB each
    __shared__ alignas(16) unsigned short Vs[3][64 * 64];   // 8 KB each
    const int tid = threadIdx.x, wv = tid >> 6, l = tid & 63;
    const int ql = l & 31, hi = l >> 5;
    // XCD-aware remap: 4 heads per XCD; 8 q-tiles (256 rows) per head.
    const int lid = blockIdx.x;
    const int xcd = lid & 7, slot = lid >> 3;        // slot 0..31
    const int bh = xcd * 4 + (slot >> 3);            // 0..31 (= b*16+h)
    const int q0 = (slot & 7) * 256;
    const unsigned short* qh = q + (size_t)bh * (2048 * 64);
    AttnCtx cx;
    cx.kh = k + (size_t)bh * (2048 * 64);
    cx.vh = vT + (size_t)bh * (64 * 2048);
    cx.tid = tid; cx.ql = ql; cx.hi = hi;

    char* K0 = (char*)&Ks[0][0];
    char* K1 = (char*)&Ks[1][0];
    char* V0 = (char*)&Vs[0][0];
    char* V1 = (char*)&Vs[1][0];
    char* V2 = (char*)&Vs[2][0];
    auto VB = [&](int i) -> char* { return i == 0 ? V0 : (i == 1 ? V1 : V2); };

    // Q fragments for both Q-blocks: rows qrow0 and qrow0+32
    const int qrow0 = q0 + wv * 64 + ql;
    short8 qv0[4], qv1[4];
#pragma unroll
    for (int c = 0; c < 4; ++c) {
        qv0[c] = *(const short8*)&qh[(size_t)qrow0 * 64 + c * 16 + hi * 8];
        qv1[c] = *(const short8*)&qh[(size_t)(qrow0 + 32) * 64 + c * 16 + hi * 8];
    }

    f32x16 accO0[2] = {}, accO1[2] = {};
    float lrun0 = 0.0f, lrun1 = 0.0f;
    short8 paA0[4], paA1[4], paB0[4], paB1[4];

    // ---- prologue: stage tile 0 -> K0, V0 ----
    {
#pragma unroll
        for (int p = 0; p < 2; ++p) {
            int c = p * 256 + tid;
            int row = c >> 3;
            int sxb = ((c & 7) * 16) ^ ((row & 7) << 4);
            gload_lds16(cx.kh + (size_t)row * 64 + (sxb >> 1), K0 + c * 16);
        }
#pragma unroll
        for (int p = 0; p < 2; ++p) {
            int c = p * 256 + tid;
            int d = c >> 3;
            int sxb = ((c & 7) * 16) ^ ((d & 7) << 4);
            gload_lds16(cx.vh + (size_t)d * 2048 + (sxb >> 1), V0 + c * 16);
        }
    }

    // V ring: at step t, tile t lives in slot t%3; Vprv = slot (t-1)%3.
    int vp = 2, vc = 0, vn = 1;
    auto rot = [&]() { vp = vc; vc = vn; vn = (vn == 2) ? 0 : vn + 1; };

    attn_step<false, true>(cx, 64, K0, nullptr, K1, VB(vn),
                           qv0, qv1, paB0, paB1, paA0, paA1,
                           accO0, accO1, lrun0, lrun1);
    rot();
    for (int t = 1; t < 31; t += 2) {
        attn_step<true, true>(cx, (t + 1) * 64, K1, VB(vp), K0, VB(vn),
                              qv0, qv1, paA0, paA1, paB0, paB1,
                              accO0, accO1, lrun0, lrun1);
        rot();
        attn_step<true, true>(cx, (t + 2) * 64, K0, VB(vp), K1, VB(vn),
                              qv0, qv1, paB0, paB1, paA0, paA1,
                              accO0, accO1, lrun0, lrun1);
        rot();
    }
    attn_step<true, false>(cx, 0, K1, VB(vp), nullptr, nullptr,
                           qv0, qv1, paA0, paA1, paB0, paB1,
                           accO0, accO1, lrun0, lrun1);
    // final PV(31): tile 31 lives in slot 31%3 == vc (no rot after last step)
    {
        const char* Vlast = VB(vc);
#pragma unroll
        for (int n = 0; n < 2; ++n) {
            int d = n * 32 + ql;
#pragma unroll
            for (int kc = 0; kc < 4; ++kc) {
                int bo = (d * 128 + kc * 32 + hi * 16) ^ ((d & 7) << 4);
                short8 va = *(const short8*)(Vlast + bo);
                accO0[n] = mfma32(va, paB0[kc], accO0[n]);
                accO1[n] = mfma32(va, paB1[kc], accO1[n]);
            }
        }
    }

    // ---- epilogue: normalize, scatter to [t*2+b][h*64+d] bf16 ----
    const float inv0 = 1.0f / (lrun0 + __shfl_xor(lrun0, 32));
    const float inv1 = 1.0f / (lrun1 + __shfl_xor(lrun1, 32));
    const int b = bh >> 4, h = bh & 15;
    const int orow0 = qrow0 * 2 + b;
#pragma unroll
    for (int n = 0; n < 2; ++n)
#pragma unroll
        for (int rq = 0; rq < 4; ++rq) {
            uint2 u;
            u.x = cvt_pk_bf16(accO0[n][rq * 4 + 0] * inv0, accO0[n][rq * 4 + 1] * inv0);
            u.y = cvt_pk_bf16(accO0[n][rq * 4 + 2] * inv0, accO0[n][rq * 4 + 3] * inv0);
            *(uint2*)&outb[(size_t)orow0 * 1024 + h * 64 + n * 32 + rq * 8 + hi * 4] = u;
            uint2 w;
            w.x = cvt_pk_bf16(accO1[n][rq * 4 + 0] * inv1, accO1[n][rq * 4 + 1] * inv1);
            w.y = cvt_pk_bf16(accO1[n][rq * 4 + 2] * inv1, accO1[n][rq * 4 + 3] * inv1);
            *(uint2*)&outb[(size_t)(orow0 + 64) * 1024 + h * 64 + n * 32 + rq * 8 + hi * 4] = w;
        }
}

// ---------------------------------------------------------------------------
extern "C" void kernel_launch(void* const* d_in, const int* in_sizes, int n_in,
                              void* d_out, int out_size, void* d_ws, size_t ws_size,
                              hipStream_t stream) {
    const float* X  = (const float*)d_in[0];
    const float* Wq = (const float*)d_in[1];
    const float* bq = (const float*)d_in[2];
    const float* Wk = (const float*)d_in[3];
    const float* bk = (const float*)d_in[4];
    const float* Wv = (const float*)d_in[5];
    const float* bv = (const float*)d_in[6];
    const float* Wo = (const float*)d_in[7];
    const float* bo = (const float*)d_in[8];
    float* out = (float*)d_out;

    char* ws = (char*)d_ws;
    if (ws_size < ((size_t)49 << 20)) return;   // need ~48.1 MB scratch
    unsigned short* Xbf   = (unsigned short*)(ws);                       // 8 MB
    unsigned short* Wcat  = (unsigned short*)(ws + ((size_t)8  << 20));  // 6 MB
    unsigned short* Wobf  = (unsigned short*)(ws + ((size_t)14 << 20));  // 2 MB
    unsigned short* qb    = (unsigned short*)(ws + ((size_t)16 << 20));  // q, k, vTp (8 MB each)
    unsigned short* ab    = (unsigned short*)(ws + ((size_t)40 << 20));  // 8 MB
    float*          biasq = (float*)(ws + ((size_t)48 << 20));           // 12 KB
    unsigned short* kb  = qb + (size_t)HEAD_ELEMS;
    unsigned short* vTb = qb + (size_t)2 * HEAD_ELEMS;

    cast_all<<<4096, 256, 0, stream>>>(X, Wq, Wk, Wv, Wo, Xbf, Wcat, Wobf);
    bias_fuse<<<12, 256, 0, stream>>>(bq, bk, bv, biasq);
    gemm_bt<0><<<dim3((M_ROWS / 128) * (QKV_N / 128)), 256, 0, stream>>>(
        Xbf, Wcat, biasq, (void*)qb, M_ROWS, QKV_N, E_DIM);
    attn_fwd<<<dim3(32 * 8), 256, 0, stream>>>(qb, kb, vTb, ab);
    gemm_bt<1><<<dim3((M_ROWS / 128) * (E_DIM / 128)), 256, 0, stream>>>(
        ab, Wobf, bo, (void*)out, M_ROWS, E_DIM, E_DIM);
}

// Round 13
// 119.368 us; speedup vs baseline: 1.7319x; 1.0626x over previous
//
#include <hip/hip_runtime.h>
#include <hip/hip_bf16.h>

// ---------------------------------------------------------------------------
// MultiheadAttention: [T=2048, B=2, E=1024], H=16, D=64
// R13: ONE barrier per pipeline step everywhere. Attn: K 3-slot + V 4-slot
// LDS rings (stage t+2 while computing t; deferred PV reads V(t-1) safely).
// GEMMs: 3-slot rings, same single-sync schedule. Everything else = R8:
// swapped-QK^T 32x32x16, sigma-permuted V (lane-local P frags), no-max exp2
// softmax, cross-tile PV defer, XCD remap, setprio, counted vmcnt(4).
// ---------------------------------------------------------------------------

typedef __attribute__((ext_vector_type(8))) short short8;
typedef __attribute__((ext_vector_type(4))) float f32x4;
typedef __attribute__((ext_vector_type(16))) float f32x16;
typedef __attribute__((ext_vector_type(4))) unsigned u32x4;

#define T_DIM 2048
#define B_DIM 2
#define E_DIM 1024
#define H_DIM 16
#define D_DIM 64
#define M_ROWS (T_DIM * B_DIM)      // 4096
#define QKV_N (3 * E_DIM)           // 3072
#define HEAD_ELEMS (32 * 2048 * 64) // per q/k/v buffer elements (4,194,304)
#define LOG2E 1.44269504088896340736f

__device__ __forceinline__ unsigned short f2bf(float f) {
    unsigned u = __builtin_bit_cast(unsigned, f);
    unsigned r = (u + 0x7fffu + ((u >> 16) & 1u)) >> 16;
    return (unsigned short)r;
}

__device__ __forceinline__ unsigned cvt_pk_bf16(float lo, float hi) {
    unsigned d;
    asm("v_cvt_pk_bf16_f32 %0, %1, %2" : "=v"(d) : "v"(lo), "v"(hi));
    return d;
}

__device__ __forceinline__ void gload_lds16(const void* g, void* l) {
    __builtin_amdgcn_global_load_lds(
        (const __attribute__((address_space(1))) void*)g,
        (__attribute__((address_space(3))) void*)l, 16, 0, 0);
}

__device__ __forceinline__ f32x16 mfma32(short8 a, short8 b, f32x16 c) {
    return __builtin_amdgcn_mfma_f32_32x32x16_bf16(a, b, c, 0, 0, 0);
}

// ---------------------------------------------------------------------------
// Cast / pack kernel. Wq gets 0.125 * log2(e) so softmax can use exp2.
// ---------------------------------------------------------------------------
__global__ __launch_bounds__(256) void cast_all(
    const float* __restrict__ X,
    const float* __restrict__ Wq, const float* __restrict__ Wk,
    const float* __restrict__ Wv, const float* __restrict__ Wo,
    unsigned short* __restrict__ Xbf,
    unsigned short* __restrict__ Wcat,
    unsigned short* __restrict__ Wobf)
{
    int idx = blockIdx.x * 256 + threadIdx.x;      // 0 .. 1M-1
    size_t base = (size_t)idx * 8;
    int row = (int)(base >> 10);
    int col = (int)(base & 1023);
    const float* src;
    unsigned short* dst;
    float scale = 1.0f;
    if (row < 4096) {
        src = X + base;
        dst = Xbf + base;
    } else if (row < 7168) {
        int wrow = row - 4096;                      // 0..3071
        if (wrow < 1024)      { src = Wq + ((size_t)wrow << 10) + col; scale = 0.125f * LOG2E; }
        else if (wrow < 2048) { src = Wk + ((size_t)(wrow - 1024) << 10) + col; }
        else                  { src = Wv + ((size_t)(wrow - 2048) << 10) + col; }
        dst = Wcat + ((size_t)wrow << 10) + col;
    } else {
        int wrow = row - 7168;                      // 0..1023
        src = Wo + ((size_t)wrow << 10) + col;
        dst = Wobf + ((size_t)wrow << 10) + col;
    }
    float4 f0 = *(const float4*)src;
    float4 f1 = *(const float4*)(src + 4);
    short8 r;
    r[0] = (short)f2bf(f0.x * scale);
    r[1] = (short)f2bf(f0.y * scale);
    r[2] = (short)f2bf(f0.z * scale);
    r[3] = (short)f2bf(f0.w * scale);
    r[4] = (short)f2bf(f1.x * scale);
    r[5] = (short)f2bf(f1.y * scale);
    r[6] = (short)f2bf(f1.z * scale);
    r[7] = (short)f2bf(f1.w * scale);
    *(short8*)dst = r;
}

__global__ __launch_bounds__(256) void bias_fuse(
    const float* __restrict__ bq, const float* __restrict__ bk,
    const float* __restrict__ bv, float* __restrict__ biasq)
{
    int i = blockIdx.x * 256 + threadIdx.x;
    if (i < 1024)       biasq[i] = 0.125f * LOG2E * bq[i];
    else if (i < 2048)  biasq[i] = bk[i - 1024];
    else if (i < 3072)  biasq[i] = bv[i - 2048];
}

// ---------------------------------------------------------------------------
// GEMM: C[M,N] = A[M,K] @ B[N,K]^T + bias[N]
//   MODE 0: q,k -> [BH][T][D] bf16 ; v -> transposed+key-permuted vTp[BH][D][T]
//   MODE 1: out = fp32 row-major [M][N]
// 128x128 tile, BK=32, 3-slot LDS ring, ONE barrier per K-step, vmcnt(4).
// ---------------------------------------------------------------------------
template <int MODE>
__global__ __launch_bounds__(256) void gemm_bt(
    const unsigned short* __restrict__ A,
    const unsigned short* __restrict__ B,
    const float* __restrict__ bias,
    void* __restrict__ outp,
    int M, int N, int K)
{
    __shared__ alignas(16) unsigned short As[3][128 * 32];
    __shared__ alignas(16) unsigned short Bs[3][128 * 32];
    const int tid = threadIdx.x;
    const int wave = tid >> 6, lane = tid & 63;
    const int lr = lane & 15, lg = lane >> 4;
    const int nbx = N >> 7;
    const int bx = blockIdx.x % nbx, by = blockIdx.x / nbx;
    const int wr = wave >> 1, wc = wave & 1;

    f32x4 acc[4][4] = {};

    auto stage = [&](int slot, int kt) {
#pragma unroll
        for (int pass = 0; pass < 2; ++pass) {
            int c = pass * 256 + wave * 64 + lane;       // 16B chunk id 0..511
            int row = c >> 2, kc = c & 3;
            gload_lds16(A + (size_t)(by * 128 + row) * K + kt + kc * 8,
                        (char*)&As[slot][0] + c * 16);
            gload_lds16(B + (size_t)(bx * 128 + row) * K + kt + kc * 8,
                        (char*)&Bs[slot][0] + c * 16);
        }
    };

    const int NK = K >> 5;
    stage(0, 0);
    stage(1, 32);
    int s3 = 0;
    for (int ki = 0; ki < NK; ++ki) {
        asm volatile("s_waitcnt lgkmcnt(0)" ::: "memory");
        if (ki < NK - 1) asm volatile("s_waitcnt vmcnt(4)" ::: "memory");
        else             asm volatile("s_waitcnt vmcnt(0)" ::: "memory");
        __builtin_amdgcn_s_barrier();
        __builtin_amdgcn_sched_barrier(0);
        if (ki + 2 < NK) {
            int ns = s3 + 2; if (ns >= 3) ns -= 3;
            stage(ns, (ki + 2) * 32);
        }

        short8 af[4], bf[4];
#pragma unroll
        for (int m = 0; m < 4; ++m)
            af[m] = *(const short8*)&As[s3][(wr * 64 + m * 16 + lr) * 32 + lg * 8];
#pragma unroll
        for (int n = 0; n < 4; ++n)
            bf[n] = *(const short8*)&Bs[s3][(wc * 64 + n * 16 + lr) * 32 + lg * 8];
        __builtin_amdgcn_s_setprio(1);
#pragma unroll
        for (int m = 0; m < 4; ++m)
#pragma unroll
            for (int n = 0; n < 4; ++n)
                acc[m][n] = __builtin_amdgcn_mfma_f32_16x16x32_bf16(af[m], bf[n], acc[m][n], 0, 0, 0);
        __builtin_amdgcn_s_setprio(0);

        s3 = (s3 + 1 == 3) ? 0 : s3 + 1;
    }

    const int gcol0 = bx * 128 + wc * 64;
    const int grow0 = by * 128 + wr * 64;
    if (MODE == 0) {
        unsigned short* qb = (unsigned short*)outp;
#pragma unroll
        for (int m = 0; m < 4; ++m) {
#pragma unroll
            for (int n = 0; n < 4; ++n) {
                int col = gcol0 + n * 16 + lr;           // 0..3071
                float bsv = bias[col];
                int which = col >> 10;
                int e = col & 1023;
                int h = e >> 6, d = e & 63;
                if (which < 2) {
                    unsigned short* bufb = qb + (size_t)which * HEAD_ELEMS;
#pragma unroll
                    for (int j = 0; j < 4; ++j) {
                        int r = grow0 + m * 16 + lg * 4 + j; // 0..4095 = t*2+b
                        int t = r >> 1, b = r & 1;
                        int bh = b * 16 + h;
                        bufb[((size_t)bh * 2048 + t) * 64 + d] = f2bf(acc[m][n][j] + bsv);
                    }
                } else {
                    // v: write transposed vTp[bh][d][t] with key bits2,3 swapped;
                    // pack (t0, t0+1) per dword -> swap dword-index bits 1,2.
                    unsigned* vT32 = (unsigned*)(qb + (size_t)2 * HEAD_ELEMS);
                    int t0 = (grow0 + m * 16 + lg * 4) >> 1;    // even
                    int dwidx = t0 >> 1;
                    int dwp = (dwidx & ~6) | ((dwidx & 2) << 1) | ((dwidx & 4) >> 1);
                    unsigned w0 = (unsigned)f2bf(acc[m][n][0] + bsv) |
                                  ((unsigned)f2bf(acc[m][n][2] + bsv) << 16);  // b=0
                    unsigned w1 = (unsigned)f2bf(acc[m][n][1] + bsv) |
                                  ((unsigned)f2bf(acc[m][n][3] + bsv) << 16);  // b=1
                    vT32[(size_t)(h * 64 + d) * 1024 + dwp] = w0;
                    vT32[(size_t)((16 + h) * 64 + d) * 1024 + dwp] = w1;
                }
            }
        }
    } else {
        float* O = (float*)outp;
#pragma unroll
        for (int m = 0; m < 4; ++m) {
#pragma unroll
            for (int n = 0; n < 4; ++n) {
                int col = gcol0 + n * 16 + lr;
                float bsv = bias[col];
#pragma unroll
                for (int j = 0; j < 4; ++j) {
                    int r = grow0 + m * 16 + lg * 4 + j;
                    O[(size_t)r * N + col] = acc[m][n][j] + bsv;
                }
            }
        }
    }
}

// ---------------------------------------------------------------------------
// Flash attention: grid = 32 bh x 16 q-tiles(128 rows), 4 waves x 32 q-rows.
// K 3-slot ring (24KB), V 4-slot ring (32KB): ONE barrier per KV step.
// Step t: lgkm(0); vmcnt(4); barrier; stage(t+2); QK(t); PV(t-1) from LDS;
// softmax(no max, exp2); pack. V(t-1) survives because stage hits (t+2)%4.
// ---------------------------------------------------------------------------
struct AttnCtx {
    const unsigned short* kh;
    const unsigned short* vh;
    int tid, ql, hi;
};

template<bool DO_PV, bool DO_STAGE, bool LASTWAIT>
__device__ __forceinline__ void attn_step(
    const AttnCtx& cx, int kt_next,
    const char* Kb, const char* Vprv, char* Kst, char* Vst,
    const short8 (&qv)[4],
    const short8 (&paP)[4], short8 (&paC)[4],
    f32x16 (&accO)[2], float& lrun)
{
    const int tid = cx.tid, ql = cx.ql, hi = cx.hi;
    asm volatile("s_waitcnt lgkmcnt(0)" ::: "memory");
    if constexpr (LASTWAIT) asm volatile("s_waitcnt vmcnt(0)" ::: "memory");
    else                    asm volatile("s_waitcnt vmcnt(4)" ::: "memory");
    __builtin_amdgcn_s_barrier();
    __builtin_amdgcn_sched_barrier(0);

    if constexpr (DO_STAGE) {
#pragma unroll
        for (int p = 0; p < 2; ++p) {          // K tile [64 k][64 d]
            int c = p * 256 + tid;
            int row = c >> 3;
            int sxb = ((c & 7) * 16) ^ ((row & 7) << 4);
            gload_lds16(cx.kh + (size_t)(kt_next + row) * 64 + (sxb >> 1), Kst + c * 16);
        }
#pragma unroll
        for (int p = 0; p < 2; ++p) {          // V^T tile [64 d][64 k]
            int c = p * 256 + tid;
            int d = c >> 3;
            int sxb = ((c & 7) * 16) ^ ((d & 7) << 4);
            gload_lds16(cx.vh + (size_t)d * 2048 + kt_next + (sxb >> 1), Vst + c * 16);
        }
    }

    // ---- S^T = K Q^T (matrix pipe) ----
    f32x16 st[2] = {};
    __builtin_amdgcn_s_setprio(1);
#pragma unroll
    for (int m = 0; m < 2; ++m) {
        int krow = m * 32 + ql;
#pragma unroll
        for (int c = 0; c < 4; ++c) {
            int bo = (krow * 128 + c * 32 + hi * 16) ^ ((krow & 7) << 4);
            short8 ka = *(const short8*)(Kb + bo);
            st[m] = mfma32(ka, qv[c], st[m]);
        }
    }
    // ---- deferred PV of PREVIOUS tile, V from ring slot (t-1)%4 ----
    if constexpr (DO_PV) {
#pragma unroll
        for (int n = 0; n < 2; ++n) {
            int d = n * 32 + ql;
#pragma unroll
            for (int kc = 0; kc < 4; ++kc) {
                int bo = (d * 128 + kc * 32 + hi * 16) ^ ((d & 7) << 4);
                short8 va = *(const short8*)(Vprv + bo);
                accO[n] = mfma32(va, paP[kc], accO[n]);
            }
        }
    }
    __builtin_amdgcn_s_setprio(0);
    __builtin_amdgcn_sched_barrier(0);

    // ---- softmax numerator: P = exp2(S), 4-way partial sums (no max) ----
    float rs0 = 0.f, rs1 = 0.f, rs2 = 0.f, rs3 = 0.f;
#pragma unroll
    for (int m = 0; m < 2; ++m) {
#pragma unroll
        for (int r = 0; r < 16; r += 4) {
            float e0 = __builtin_amdgcn_exp2f(st[m][r + 0]);
            float e1 = __builtin_amdgcn_exp2f(st[m][r + 1]);
            float e2 = __builtin_amdgcn_exp2f(st[m][r + 2]);
            float e3 = __builtin_amdgcn_exp2f(st[m][r + 3]);
            st[m][r + 0] = e0; st[m][r + 1] = e1;
            st[m][r + 2] = e2; st[m][r + 3] = e3;
            rs0 += e0; rs1 += e1; rs2 += e2; rs3 += e3;
        }
    }
    lrun += (rs0 + rs1) + (rs2 + rs3);

    // ---- pack P (lane-local thanks to key permutation) ----
#pragma unroll
    for (int kc = 0; kc < 4; ++kc) {
        int m = kc >> 1, b8 = (kc & 1) * 8;
        u32x4 u;
        u[0] = cvt_pk_bf16(st[m][b8 + 0], st[m][b8 + 1]);
        u[1] = cvt_pk_bf16(st[m][b8 + 2], st[m][b8 + 3]);
        u[2] = cvt_pk_bf16(st[m][b8 + 4], st[m][b8 + 5]);
        u[3] = cvt_pk_bf16(st[m][b8 + 6], st[m][b8 + 7]);
        paC[kc] = __builtin_bit_cast(short8, u);
    }
}

__global__ __launch_bounds__(256, 2) void attn_fwd(
    const unsigned short* __restrict__ q,
    const unsigned short* __restrict__ k,
    const unsigned short* __restrict__ vT,
    unsigned short* __restrict__ outb)   // [4096][1024] bf16, row=t*2+b, col=h*64+d
{
    __shared__ alignas(16) unsigned short Ks[3][64 * 64];   // 8 KB each
    __shared__ alignas(16) unsigned short Vs[4][64 * 64];   // 8 KB each
    const int tid = threadIdx.x, wv = tid >> 6, l = tid & 63;
    const int ql = l & 31, hi = l >> 5;
    // XCD-aware remap: 4 heads per XCD, 16 q-tiles per head co-resident.
    const int lid = blockIdx.x;
    const int xcd = lid & 7, slot = lid >> 3;      // slot 0..63
    const int bh = xcd * 4 + (slot >> 4);          // 0..31 (= b*16+h)
    const int q0 = (slot & 15) * 128;
    const unsigned short* qh = q + (size_t)bh * (2048 * 64);
    AttnCtx cx;
    cx.kh = k + (size_t)bh * (2048 * 64);
    cx.vh = vT + (size_t)bh * (64 * 2048);
    cx.tid = tid; cx.ql = ql; cx.hi = hi;

#define KSLOT(i) ((char*)&Ks[i][0])
#define VSLOT(i) ((char*)&Vs[i][0])

    // Q fragments: B-frag col = q (lane&31), k-elem = c*16 + hi*8 + e
    const int qrow = q0 + wv * 32 + ql;
    short8 qv[4];
#pragma unroll
    for (int c = 0; c < 4; ++c)
        qv[c] = *(const short8*)&qh[(size_t)qrow * 64 + c * 16 + hi * 8];

    f32x16 accO[2] = {};
    float lrun = 0.0f;
    short8 paA[4], paB[4];

    // ---- prologue: stage tiles 0 and 1 ----
#pragma unroll
    for (int tt = 0; tt < 2; ++tt) {
#pragma unroll
        for (int p = 0; p < 2; ++p) {
            int c = p * 256 + tid;
            int row = c >> 3;
            int sxb = ((c & 7) * 16) ^ ((row & 7) << 4);
            gload_lds16(cx.kh + (size_t)(tt * 64 + row) * 64 + (sxb >> 1),
                        KSLOT(tt) + c * 16);
        }
#pragma unroll
        for (int p = 0; p < 2; ++p) {
            int c = p * 256 + tid;
            int d = c >> 3;
            int sxb = ((c & 7) * 16) ^ ((d & 7) << 4);
            gload_lds16(cx.vh + (size_t)d * 2048 + tt * 64 + (sxb >> 1),
                        VSLOT(tt) + c * 16);
        }
    }

    // slot indices: k3 = t%3, v4 = t%4, advanced after every step.
    int k3 = 0, v4 = 0;
    auto adv = [&]() { k3 = (k3 + 1 == 3) ? 0 : k3 + 1; v4 = (v4 + 1) & 3; };

    // t = 0: stage tile 2, no PV, pack -> paA
    attn_step<false, true, false>(cx, 2 * 64, KSLOT(0), nullptr,
                                  KSLOT(2), VSLOT(2),
                                  qv, paB, paA, accO, lrun);
    adv();
    // pairs (t, t+1) for t = 1,3,...,27  (stages tiles 3..30)
    for (int t = 1; t <= 27; t += 2) {
        int ns3 = (k3 + 2 >= 3) ? k3 - 1 : k3 + 2;
        attn_step<true, true, false>(cx, (t + 2) * 64,
                                     KSLOT(k3), VSLOT((v4 + 3) & 3),
                                     KSLOT(ns3), VSLOT((v4 + 2) & 3),
                                     qv, paA, paB, accO, lrun);
        adv();
        ns3 = (k3 + 2 >= 3) ? k3 - 1 : k3 + 2;
        attn_step<true, true, false>(cx, (t + 3) * 64,
                                     KSLOT(k3), VSLOT((v4 + 3) & 3),
                                     KSLOT(ns3), VSLOT((v4 + 2) & 3),
                                     qv, paB, paA, accO, lrun);
        adv();
    }
    // t = 29: stage tile 31; P=paA, C=paB
    {
        int ns3 = (k3 + 2 >= 3) ? k3 - 1 : k3 + 2;
        attn_step<true, true, false>(cx, 31 * 64,
                                     KSLOT(k3), VSLOT((v4 + 3) & 3),
                                     KSLOT(ns3), VSLOT((v4 + 2) & 3),
                                     qv, paA, paB, accO, lrun);
        adv();
    }
    // t = 30: no stage; P=paB, C=paA
    attn_step<true, false, false>(cx, 0, KSLOT(k3), VSLOT((v4 + 3) & 3),
                                  nullptr, nullptr,
                                  qv, paB, paA, accO, lrun);
    adv();
    // t = 31: no stage, final wait; P=paA, C=paB
    attn_step<true, false, true>(cx, 0, KSLOT(k3), VSLOT((v4 + 3) & 3),
                                 nullptr, nullptr,
                                 qv, paA, paB, accO, lrun);
    // final PV(31): tile 31 lives in V slot 31%4 = 3
#pragma unroll
    for (int n = 0; n < 2; ++n) {
        int d = n * 32 + ql;
#pragma unroll
        for (int kc = 0; kc < 4; ++kc) {
            int bo = (d * 128 + kc * 32 + hi * 16) ^ ((d & 7) << 4);
            short8 va = *(const short8*)(VSLOT(3) + bo);
            accO[n] = mfma32(va, paB[kc], accO[n]);
        }
    }

    // ---- epilogue: normalize, scatter to [t*2+b][h*64+d] bf16 ----
    const float ltot = lrun + __shfl_xor(lrun, 32);
    const float inv = 1.0f / ltot;
    const int b = bh >> 4, h = bh & 15;
    const int orow = qrow * 2 + b;
#pragma unroll
    for (int n = 0; n < 2; ++n)
#pragma unroll
        for (int rq = 0; rq < 4; ++rq) {
            uint2 u;
            u.x = cvt_pk_bf16(accO[n][rq * 4 + 0] * inv, accO[n][rq * 4 + 1] * inv);
            u.y = cvt_pk_bf16(accO[n][rq * 4 + 2] * inv, accO[n][rq * 4 + 3] * inv);
            *(uint2*)&outb[(size_t)orow * 1024 + h * 64 + n * 32 + rq * 8 + hi * 4] = u;
        }
#undef KSLOT
#undef VSLOT
}

// ---------------------------------------------------------------------------
extern "C" void kernel_launch(void* const* d_in, const int* in_sizes, int n_in,
                              void* d_out, int out_size, void* d_ws, size_t ws_size,
                              hipStream_t stream) {
    const float* X  = (const float*)d_in[0];
    const float* Wq = (const float*)d_in[1];
    const float* bq = (const float*)d_in[2];
    const float* Wk = (const float*)d_in[3];
    const float* bk = (const float*)d_in[4];
    const float* Wv = (const float*)d_in[5];
    const float* bv = (const float*)d_in[6];
    const float* Wo = (const float*)d_in[7];
    const float* bo = (const float*)d_in[8];
    float* out = (float*)d_out;

    char* ws = (char*)d_ws;
    if (ws_size < ((size_t)49 << 20)) return;   // need ~48.1 MB scratch
    unsigned short* Xbf   = (unsigned short*)(ws);                       // 8 MB
    unsigned short* Wcat  = (unsigned short*)(ws + ((size_t)8  << 20));  // 6 MB
    unsigned short* Wobf  = (unsigned short*)(ws + ((size_t)14 << 20));  // 2 MB
    unsigned short* qb    = (unsigned short*)(ws + ((size_t)16 << 20));  // q, k, vTp (8 MB each)
    unsigned short* ab    = (unsigned short*)(ws + ((size_t)40 << 20));  // 8 MB
    float*          biasq = (float*)(ws + ((size_t)48 << 20));           // 12 KB
    unsigned short* kb  = qb + (size_t)HEAD_ELEMS;
    unsigned short* vTb = qb + (size_t)2 * HEAD_ELEMS;

    cast_all<<<4096, 256, 0, stream>>>(X, Wq, Wk, Wv, Wo, Xbf, Wcat, Wobf);
    bias_fuse<<<12, 256, 0, stream>>>(bq, bk, bv, biasq);
    gemm_bt<0><<<dim3((M_ROWS / 128) * (QKV_N / 128)), 256, 0, stream>>>(
        Xbf, Wcat, biasq, (void*)qb, M_ROWS, QKV_N, E_DIM);
    attn_fwd<<<dim3(32 * 16), 256, 0, stream>>>(qb, kb, vTb, ab);
    gemm_bt<1><<<dim3((M_ROWS / 128) * (E_DIM / 128)), 256, 0, stream>>>(
        ab, Wobf, bo, (void*)out, M_ROWS, E_DIM, E_DIM);
}

// Round 14
// 115.764 us; speedup vs baseline: 1.7858x; 1.0311x over previous
//
#include <hip/hip_runtime.h>
#include <hip/hip_bf16.h>

// ---------------------------------------------------------------------------
// MultiheadAttention: [T=2048, B=2, E=1024], H=16, D=64
// R14: drain-free pipelines. Attn: K and V in 4-slot LDS rings (compile-time
// slot indices via 4-step unroll); PV(t-1) reads V from LDS in-step, so every
// ds_read's consumer precedes the barrier -> NO lgkmcnt(0) drains anywhere;
// one vmcnt(4)+s_barrier per step. GEMMs: 3-slot rings (3-step unroll), same
// drain removal. bias_fuse folded into cast_all. Rest as R8: swapped-QK^T
// 32x32x16, sigma-permuted V (lane-local P frags), no-max exp2 softmax,
// cross-tile PV defer, XCD remap, setprio.
// ---------------------------------------------------------------------------

typedef __attribute__((ext_vector_type(8))) short short8;
typedef __attribute__((ext_vector_type(4))) float f32x4;
typedef __attribute__((ext_vector_type(16))) float f32x16;
typedef __attribute__((ext_vector_type(4))) unsigned u32x4;

#define T_DIM 2048
#define B_DIM 2
#define E_DIM 1024
#define H_DIM 16
#define D_DIM 64
#define M_ROWS (T_DIM * B_DIM)      // 4096
#define QKV_N (3 * E_DIM)           // 3072
#define HEAD_ELEMS (32 * 2048 * 64) // per q/k/v buffer elements (4,194,304)
#define LOG2E 1.44269504088896340736f

__device__ __forceinline__ unsigned short f2bf(float f) {
    unsigned u = __builtin_bit_cast(unsigned, f);
    unsigned r = (u + 0x7fffu + ((u >> 16) & 1u)) >> 16;
    return (unsigned short)r;
}

__device__ __forceinline__ unsigned cvt_pk_bf16(float lo, float hi) {
    unsigned d;
    asm("v_cvt_pk_bf16_f32 %0, %1, %2" : "=v"(d) : "v"(lo), "v"(hi));
    return d;
}

__device__ __forceinline__ void gload_lds16(const void* g, void* l) {
    __builtin_amdgcn_global_load_lds(
        (const __attribute__((address_space(1))) void*)g,
        (__attribute__((address_space(3))) void*)l, 16, 0, 0);
}

__device__ __forceinline__ f32x16 mfma32(short8 a, short8 b, f32x16 c) {
    return __builtin_amdgcn_mfma_f32_32x32x16_bf16(a, b, c, 0, 0, 0);
}

// ---------------------------------------------------------------------------
// Cast / pack kernel (+ fused qkv-bias pack in the extra block).
// Wq/bq get 0.125 * log2(e) so softmax can use exp2.
// ---------------------------------------------------------------------------
__global__ __launch_bounds__(256) void cast_all(
    const float* __restrict__ X,
    const float* __restrict__ Wq, const float* __restrict__ Wk,
    const float* __restrict__ Wv, const float* __restrict__ Wo,
    const float* __restrict__ bq, const float* __restrict__ bk,
    const float* __restrict__ bv,
    unsigned short* __restrict__ Xbf,
    unsigned short* __restrict__ Wcat,
    unsigned short* __restrict__ Wobf,
    float* __restrict__ biasq)
{
    int idx = blockIdx.x * 256 + threadIdx.x;      // 0 .. 1M-1 (+ bias block)
    if (idx >= (1 << 20)) {
        int i = idx - (1 << 20);                   // 0..255
        for (int j = i; j < 3072; j += 256) {
            float v;
            if (j < 1024)       v = 0.125f * LOG2E * bq[j];
            else if (j < 2048)  v = bk[j - 1024];
            else                v = bv[j - 2048];
            biasq[j] = v;
        }
        return;
    }
    size_t base = (size_t)idx * 8;
    int row = (int)(base >> 10);
    int col = (int)(base & 1023);
    const float* src;
    unsigned short* dst;
    float scale = 1.0f;
    if (row < 4096) {
        src = X + base;
        dst = Xbf + base;
    } else if (row < 7168) {
        int wrow = row - 4096;                      // 0..3071
        if (wrow < 1024)      { src = Wq + ((size_t)wrow << 10) + col; scale = 0.125f * LOG2E; }
        else if (wrow < 2048) { src = Wk + ((size_t)(wrow - 1024) << 10) + col; }
        else                  { src = Wv + ((size_t)(wrow - 2048) << 10) + col; }
        dst = Wcat + ((size_t)wrow << 10) + col;
    } else {
        int wrow = row - 7168;                      // 0..1023
        src = Wo + ((size_t)wrow << 10) + col;
        dst = Wobf + ((size_t)wrow << 10) + col;
    }
    float4 f0 = *(const float4*)src;
    float4 f1 = *(const float4*)(src + 4);
    short8 r;
    r[0] = (short)f2bf(f0.x * scale);
    r[1] = (short)f2bf(f0.y * scale);
    r[2] = (short)f2bf(f0.z * scale);
    r[3] = (short)f2bf(f0.w * scale);
    r[4] = (short)f2bf(f1.x * scale);
    r[5] = (short)f2bf(f1.y * scale);
    r[6] = (short)f2bf(f1.z * scale);
    r[7] = (short)f2bf(f1.w * scale);
    *(short8*)dst = r;
}

// ---------------------------------------------------------------------------
// GEMM: C[M,N] = A[M,K] @ B[N,K]^T + bias[N], K = 1024 (32 BK-steps).
//   MODE 0: q,k -> [BH][T][D] bf16 ; v -> transposed+key-permuted vTp[BH][D][T]
//   MODE 1: out = fp32 row-major [M][N]
// 128x128 tile, BK=32, 3-slot LDS ring w/ compile-time slots, vmcnt(4) only
// (no lgkm drains: every ds_read consumer precedes the barrier).
// ---------------------------------------------------------------------------
struct GemmCtx {
    const unsigned short* A;
    const unsigned short* B;
    int K, by, bx, wave, lane, wr, wc, lr, lg;
};

__device__ __forceinline__ void gemm_stage(
    const GemmCtx& g, unsigned short* Ast, unsigned short* Bst, int kt)
{
#pragma unroll
    for (int pass = 0; pass < 2; ++pass) {
        int c = pass * 256 + g.wave * 64 + g.lane;   // 16B chunk id 0..511
        int row = c >> 2, kc = c & 3;
        gload_lds16(g.A + (size_t)(g.by * 128 + row) * g.K + kt + kc * 8,
                    (char*)Ast + c * 16);
        gload_lds16(g.B + (size_t)(g.bx * 128 + row) * g.K + kt + kc * 8,
                    (char*)Bst + c * 16);
    }
}

template <bool DO_STAGE, bool LASTWAIT>
__device__ __forceinline__ void gemm_step(
    const GemmCtx& g,
    unsigned short* Acs, unsigned short* Bcs,
    unsigned short* Ast, unsigned short* Bst, int kt_next,
    f32x4 (&acc)[4][4])
{
    if constexpr (LASTWAIT) asm volatile("s_waitcnt vmcnt(0)" ::: "memory");
    else                    asm volatile("s_waitcnt vmcnt(4)" ::: "memory");
    __builtin_amdgcn_s_barrier();
    __builtin_amdgcn_sched_barrier(0);
    if constexpr (DO_STAGE) gemm_stage(g, Ast, Bst, kt_next);

    short8 af[4], bf[4];
#pragma unroll
    for (int m = 0; m < 4; ++m)
        af[m] = *(const short8*)&Acs[(g.wr * 64 + m * 16 + g.lr) * 32 + g.lg * 8];
#pragma unroll
    for (int n = 0; n < 4; ++n)
        bf[n] = *(const short8*)&Bcs[(g.wc * 64 + n * 16 + g.lr) * 32 + g.lg * 8];
    __builtin_amdgcn_s_setprio(1);
#pragma unroll
    for (int m = 0; m < 4; ++m)
#pragma unroll
        for (int n = 0; n < 4; ++n)
            acc[m][n] = __builtin_amdgcn_mfma_f32_16x16x32_bf16(af[m], bf[n], acc[m][n], 0, 0, 0);
    __builtin_amdgcn_s_setprio(0);
}

template <int MODE>
__global__ __launch_bounds__(256) void gemm_bt(
    const unsigned short* __restrict__ A,
    const unsigned short* __restrict__ B,
    const float* __restrict__ bias,
    void* __restrict__ outp,
    int M, int N, int K)
{
    __shared__ alignas(16) unsigned short As[3][128 * 32];
    __shared__ alignas(16) unsigned short Bs[3][128 * 32];
    const int tid = threadIdx.x;
    const int wave = tid >> 6, lane = tid & 63;
    const int lr = lane & 15, lg = lane >> 4;
    const int nbx = N >> 7;
    const int bx = blockIdx.x % nbx, by = blockIdx.x / nbx;
    const int wr = wave >> 1, wc = wave & 1;

    GemmCtx g{A, B, K, by, bx, wave, lane, wr, wc, lr, lg};
    f32x4 acc[4][4] = {};

    unsigned short *A0 = &As[0][0], *A1 = &As[1][0], *A2 = &As[2][0];
    unsigned short *B0 = &Bs[0][0], *B1 = &Bs[1][0], *B2 = &Bs[2][0];

    // prologue: stage tiles 0,1 (K assumed 1024 -> 32 tiles)
    gemm_stage(g, A0, B0, 0);
    gemm_stage(g, A1, B1, 32);
#pragma unroll 1
    for (int it = 0; it < 10; ++it) {
        int kb = it * 96;
        gemm_step<true, false>(g, A0, B0, A2, B2, kb + 64, acc);   // ki=3it
        gemm_step<true, false>(g, A1, B1, A0, B0, kb + 96, acc);   // ki=3it+1
        gemm_step<true, false>(g, A2, B2, A1, B1, kb + 128, acc);  // ki=3it+2
    }
    gemm_step<false, false>(g, A0, B0, nullptr, nullptr, 0, acc);  // ki=30
    gemm_step<false, true >(g, A1, B1, nullptr, nullptr, 0, acc);  // ki=31

    const int gcol0 = bx * 128 + wc * 64;
    const int grow0 = by * 128 + wr * 64;
    if (MODE == 0) {
        unsigned short* qb = (unsigned short*)outp;
#pragma unroll
        for (int m = 0; m < 4; ++m) {
#pragma unroll
            for (int n = 0; n < 4; ++n) {
                int col = gcol0 + n * 16 + lr;           // 0..3071
                float bsv = bias[col];
                int which = col >> 10;
                int e = col & 1023;
                int h = e >> 6, d = e & 63;
                if (which < 2) {
                    unsigned short* bufb = qb + (size_t)which * HEAD_ELEMS;
#pragma unroll
                    for (int j = 0; j < 4; ++j) {
                        int r = grow0 + m * 16 + lg * 4 + j; // 0..4095 = t*2+b
                        int t = r >> 1, b = r & 1;
                        int bh = b * 16 + h;
                        bufb[((size_t)bh * 2048 + t) * 64 + d] = f2bf(acc[m][n][j] + bsv);
                    }
                } else {
                    // v: write transposed vTp[bh][d][t] with key bits2,3 swapped;
                    // pack (t0, t0+1) per dword -> swap dword-index bits 1,2.
                    unsigned* vT32 = (unsigned*)(qb + (size_t)2 * HEAD_ELEMS);
                    int t0 = (grow0 + m * 16 + lg * 4) >> 1;    // even
                    int dwidx = t0 >> 1;
                    int dwp = (dwidx & ~6) | ((dwidx & 2) << 1) | ((dwidx & 4) >> 1);
                    unsigned w0 = (unsigned)f2bf(acc[m][n][0] + bsv) |
                                  ((unsigned)f2bf(acc[m][n][2] + bsv) << 16);  // b=0
                    unsigned w1 = (unsigned)f2bf(acc[m][n][1] + bsv) |
                                  ((unsigned)f2bf(acc[m][n][3] + bsv) << 16);  // b=1
                    vT32[(size_t)(h * 64 + d) * 1024 + dwp] = w0;
                    vT32[(size_t)((16 + h) * 64 + d) * 1024 + dwp] = w1;
                }
            }
        }
    } else {
        float* O = (float*)outp;
#pragma unroll
        for (int m = 0; m < 4; ++m) {
#pragma unroll
            for (int n = 0; n < 4; ++n) {
                int col = gcol0 + n * 16 + lr;
                float bsv = bias[col];
#pragma unroll
                for (int j = 0; j < 4; ++j) {
                    int r = grow0 + m * 16 + lg * 4 + j;
                    O[(size_t)r * N + col] = acc[m][n][j] + bsv;
                }
            }
        }
    }
}

// ---------------------------------------------------------------------------
// Flash attention: grid = 32 bh x 16 q-tiles(128 rows), 4 waves x 32 q-rows.
// K and V each in 4-slot LDS rings (64 KB total, 2 blocks/CU). Step t:
//   vmcnt(4); s_barrier; stage tile t+2 -> slot (t+2)%4;
//   QK from K[t%4]; PV(t-1) from V[(t-1)%4]; softmax (no max); pack.
// All slot indices compile-time (4-step unrolled loop). No lgkm drains:
// every ds_read's consumer (MFMA) precedes the barrier, and a slot written
// after barrier(t) was last read at step t-1 (consumers before barrier(t)).
// ---------------------------------------------------------------------------
struct AttnCtx {
    const unsigned short* kh;
    const unsigned short* vh;
    int tid, ql, hi;
};

__device__ __forceinline__ void attn_stage(
    const AttnCtx& cx, char* Kst, char* Vst, int kt)
{
#pragma unroll
    for (int p = 0; p < 2; ++p) {          // K tile [64 k][64 d]
        int c = p * 256 + cx.tid;
        int row = c >> 3;
        int sxb = ((c & 7) * 16) ^ ((row & 7) << 4);
        gload_lds16(cx.kh + (size_t)(kt + row) * 64 + (sxb >> 1), Kst + c * 16);
    }
#pragma unroll
    for (int p = 0; p < 2; ++p) {          // V^T tile [64 d][64 k]
        int c = p * 256 + cx.tid;
        int d = c >> 3;
        int sxb = ((c & 7) * 16) ^ ((d & 7) << 4);
        gload_lds16(cx.vh + (size_t)d * 2048 + kt + (sxb >> 1), Vst + c * 16);
    }
}

template<bool DO_PV, bool DO_STAGE, bool LASTWAIT>
__device__ __forceinline__ void attn_step(
    const AttnCtx& cx, int kt_next,
    const char* Kb, const char* Vprv, char* Kst, char* Vst,
    const short8 (&qv)[4],
    const short8 (&paP)[4], short8 (&paC)[4],
    f32x16 (&accO)[2], float& lrun)
{
    const int ql = cx.ql, hi = cx.hi;
    if constexpr (LASTWAIT) asm volatile("s_waitcnt vmcnt(0)" ::: "memory");
    else                    asm volatile("s_waitcnt vmcnt(4)" ::: "memory");
    __builtin_amdgcn_s_barrier();
    __builtin_amdgcn_sched_barrier(0);

    if constexpr (DO_STAGE) attn_stage(cx, Kst, Vst, kt_next);

    // ---- S^T = K Q^T (matrix pipe) ----
    f32x16 st[2] = {};
    __builtin_amdgcn_s_setprio(1);
#pragma unroll
    for (int m = 0; m < 2; ++m) {
        int krow = m * 32 + ql;
#pragma unroll
        for (int c = 0; c < 4; ++c) {
            int bo = (krow * 128 + c * 32 + hi * 16) ^ ((krow & 7) << 4);
            short8 ka = *(const short8*)(Kb + bo);
            st[m] = mfma32(ka, qv[c], st[m]);
        }
    }
    // ---- deferred PV of PREVIOUS tile, V from ring slot (t-1)%4 ----
    if constexpr (DO_PV) {
#pragma unroll
        for (int n = 0; n < 2; ++n) {
            int d = n * 32 + ql;
#pragma unroll
            for (int kc = 0; kc < 4; ++kc) {
                int bo = (d * 128 + kc * 32 + hi * 16) ^ ((d & 7) << 4);
                short8 va = *(const short8*)(Vprv + bo);
                accO[n] = mfma32(va, paP[kc], accO[n]);
            }
        }
    }
    __builtin_amdgcn_s_setprio(0);
    __builtin_amdgcn_sched_barrier(0);

    // ---- softmax numerator: P = exp2(S), 4-way partial sums (no max) ----
    float rs0 = 0.f, rs1 = 0.f, rs2 = 0.f, rs3 = 0.f;
#pragma unroll
    for (int m = 0; m < 2; ++m) {
#pragma unroll
        for (int r = 0; r < 16; r += 4) {
            float e0 = __builtin_amdgcn_exp2f(st[m][r + 0]);
            float e1 = __builtin_amdgcn_exp2f(st[m][r + 1]);
            float e2 = __builtin_amdgcn_exp2f(st[m][r + 2]);
            float e3 = __builtin_amdgcn_exp2f(st[m][r + 3]);
            st[m][r + 0] = e0; st[m][r + 1] = e1;
            st[m][r + 2] = e2; st[m][r + 3] = e3;
            rs0 += e0; rs1 += e1; rs2 += e2; rs3 += e3;
        }
    }
    lrun += (rs0 + rs1) + (rs2 + rs3);

    // ---- pack P (lane-local thanks to key permutation) ----
#pragma unroll
    for (int kc = 0; kc < 4; ++kc) {
        int m = kc >> 1, b8 = (kc & 1) * 8;
        u32x4 u;
        u[0] = cvt_pk_bf16(st[m][b8 + 0], st[m][b8 + 1]);
        u[1] = cvt_pk_bf16(st[m][b8 + 2], st[m][b8 + 3]);
        u[2] = cvt_pk_bf16(st[m][b8 + 4], st[m][b8 + 5]);
        u[3] = cvt_pk_bf16(st[m][b8 + 6], st[m][b8 + 7]);
        paC[kc] = __builtin_bit_cast(short8, u);
    }
}

__global__ __launch_bounds__(256, 2) void attn_fwd(
    const unsigned short* __restrict__ q,
    const unsigned short* __restrict__ k,
    const unsigned short* __restrict__ vT,
    unsigned short* __restrict__ outb)   // [4096][1024] bf16, row=t*2+b, col=h*64+d
{
    __shared__ alignas(16) unsigned short Ks[4][64 * 64];   // 8 KB each
    __shared__ alignas(16) unsigned short Vs[4][64 * 64];   // 8 KB each
    const int tid = threadIdx.x, wv = tid >> 6, l = tid & 63;
    const int ql = l & 31, hi = l >> 5;
    // XCD-aware remap: 4 heads per XCD, 16 q-tiles per head co-resident.
    const int lid = blockIdx.x;
    const int xcd = lid & 7, slot = lid >> 3;      // slot 0..63
    const int bh = xcd * 4 + (slot >> 4);          // 0..31 (= b*16+h)
    const int q0 = (slot & 15) * 128;
    const unsigned short* qh = q + (size_t)bh * (2048 * 64);
    AttnCtx cx;
    cx.kh = k + (size_t)bh * (2048 * 64);
    cx.vh = vT + (size_t)bh * (64 * 2048);
    cx.tid = tid; cx.ql = ql; cx.hi = hi;

    char* K0 = (char*)&Ks[0][0]; char* K1 = (char*)&Ks[1][0];
    char* K2 = (char*)&Ks[2][0]; char* K3 = (char*)&Ks[3][0];
    char* V0 = (char*)&Vs[0][0]; char* V1 = (char*)&Vs[1][0];
    char* V2 = (char*)&Vs[2][0]; char* V3 = (char*)&Vs[3][0];

    // Q fragments: B-frag col = q (lane&31), k-elem = c*16 + hi*8 + e
    const int qrow = q0 + wv * 32 + ql;
    short8 qv[4];
#pragma unroll
    for (int c = 0; c < 4; ++c)
        qv[c] = *(const short8*)&qh[(size_t)qrow * 64 + c * 16 + hi * 8];

    f32x16 accO[2] = {};
    float lrun = 0.0f;
    short8 paA[4], paB[4];

    // ---- prologue: stage tiles 0,1 -> slots 0,1 ----
    attn_stage(cx, K0, V0, 0);
    attn_stage(cx, K1, V1, 64);

    // t=0: stage tile2->slot2; QK K0; no PV; pack paA
    attn_step<false, true, false>(cx, 2 * 64, K0, nullptr, K2, V2,
                                  qv, paB, paA, accO, lrun);
    // t=1: stage tile3->slot3; QK K1; PV(V0,paA); pack paB
    attn_step<true, true, false>(cx, 3 * 64, K1, V0, K3, V3,
                                 qv, paA, paB, accO, lrun);
#pragma unroll 1
    for (int it = 0; it < 7; ++it) {
        const int t = 2 + it * 4;
        attn_step<true, true, false>(cx, (t + 2) * 64, K2, V1, K0, V0,
                                     qv, paB, paA, accO, lrun);   // t%4==2
        attn_step<true, true, false>(cx, (t + 3) * 64, K3, V2, K1, V1,
                                     qv, paA, paB, accO, lrun);   // t%4==3
        attn_step<true, true, false>(cx, (t + 4) * 64, K0, V3, K2, V2,
                                     qv, paB, paA, accO, lrun);   // t%4==0
        attn_step<true, true, false>(cx, (t + 5) * 64, K1, V0, K3, V3,
                                     qv, paA, paB, accO, lrun);   // t%4==1
    }
    // t=30: QK K2; PV(V1,paB); pack paA; no stage
    attn_step<true, false, false>(cx, 0, K2, V1, nullptr, nullptr,
                                  qv, paB, paA, accO, lrun);
    // t=31: QK K3; PV(V2,paA); pack paB; final wait
    attn_step<true, false, true>(cx, 0, K3, V2, nullptr, nullptr,
                                 qv, paA, paB, accO, lrun);
    // final PV(31): V slot 31%4 = 3, fragments paB
#pragma unroll
    for (int n = 0; n < 2; ++n) {
        int d = n * 32 + ql;
#pragma unroll
        for (int kc = 0; kc < 4; ++kc) {
            int bo = (d * 128 + kc * 32 + hi * 16) ^ ((d & 7) << 4);
            short8 va = *(const short8*)(V3 + bo);
            accO[n] = mfma32(va, paB[kc], accO[n]);
        }
    }

    // ---- epilogue: normalize, scatter to [t*2+b][h*64+d] bf16 ----
    const float ltot = lrun + __shfl_xor(lrun, 32);
    const float inv = 1.0f / ltot;
    const int b = bh >> 4, h = bh & 15;
    const int orow = qrow * 2 + b;
#pragma unroll
    for (int n = 0; n < 2; ++n)
#pragma unroll
        for (int rq = 0; rq < 4; ++rq) {
            uint2 u;
            u.x = cvt_pk_bf16(accO[n][rq * 4 + 0] * inv, accO[n][rq * 4 + 1] * inv);
            u.y = cvt_pk_bf16(accO[n][rq * 4 + 2] * inv, accO[n][rq * 4 + 3] * inv);
            *(uint2*)&outb[(size_t)orow * 1024 + h * 64 + n * 32 + rq * 8 + hi * 4] = u;
        }
}

// ---------------------------------------------------------------------------
extern "C" void kernel_launch(void* const* d_in, const int* in_sizes, int n_in,
                              void* d_out, int out_size, void* d_ws, size_t ws_size,
                              hipStream_t stream) {
    const float* X  = (const float*)d_in[0];
    const float* Wq = (const float*)d_in[1];
    const float* bq = (const float*)d_in[2];
    const float* Wk = (const float*)d_in[3];
    const float* bk = (const float*)d_in[4];
    const float* Wv = (const float*)d_in[5];
    const float* bv = (const float*)d_in[6];
    const float* Wo = (const float*)d_in[7];
    const float* bo = (const float*)d_in[8];
    float* out = (float*)d_out;

    char* ws = (char*)d_ws;
    if (ws_size < ((size_t)49 << 20)) return;   // need ~48.1 MB scratch
    unsigned short* Xbf   = (unsigned short*)(ws);                       // 8 MB
    unsigned short* Wcat  = (unsigned short*)(ws + ((size_t)8  << 20));  // 6 MB
    unsigned short* Wobf  = (unsigned short*)(ws + ((size_t)14 << 20));  // 2 MB
    unsigned short* qb    = (unsigned short*)(ws + ((size_t)16 << 20));  // q, k, vTp (8 MB each)
    unsigned short* ab    = (unsigned short*)(ws + ((size_t)40 << 20));  // 8 MB
    float*          biasq = (float*)(ws + ((size_t)48 << 20));           // 12 KB
    unsigned short* kb  = qb + (size_t)HEAD_ELEMS;
    unsigned short* vTb = qb + (size_t)2 * HEAD_ELEMS;

    cast_all<<<4097, 256, 0, stream>>>(X, Wq, Wk, Wv, Wo, bq, bk, bv,
                                       Xbf, Wcat, Wobf, biasq);
    gemm_bt<0><<<dim3((M_ROWS / 128) * (QKV_N / 128)), 256, 0, stream>>>(
        Xbf, Wcat, biasq, (void*)qb, M_ROWS, QKV_N, E_DIM);
    attn_fwd<<<dim3(32 * 16), 256, 0, stream>>>(qb, kb, vTb, ab);
    gemm_bt<1><<<dim3((M_ROWS / 128) * (E_DIM / 128)), 256, 0, stream>>>(
        ab, Wobf, bo, (void*)out, M_ROWS, E_DIM, E_DIM);
}